// Round 1
// baseline (1143.693 us; speedup 1.0000x reference)
//
#include <hip/hip_runtime.h>
#include <math.h>

#define BB 32
#define CC 256
#define TT 1024
#define KSZ 64

typedef __attribute__((ext_vector_type(4))) float f4;

// ---- workspace layout (floats) ----  total = 21,495,808 floats = 86.0 MB
static const size_t OFF_Q  = 0;               // B*T*64   q
static const size_t OFF_K  = 2097152;         // B*T*64   k
static const size_t OFF_V  = 4194304;         // B*T*256  v   (aliased: conv1 out c1)
static const size_t OFF_OA = 12582912;        // B*T*256  out_attn (aliased: conv2 out c2)
static const size_t OFF_CM = 20971520;        // B*T col max (softmax over q axis)
static const size_t OFF_CR = 21004288;        // B*T col 1/Z
static const size_t OFF_RS = 21037056;        // B*T rowsum of attn
static const size_t OFF_WX = 21069824;        // B*T weight_x
static const size_t OFF_W1 = 21102592;        // 3*256*256 normalized W1, layout [j][c][o]
static const size_t OFF_W2 = 21299200;        // 3*256*256 normalized W2

// ---------------------------------------------------------------------------
// weight-norm precompute: Wt[j][c][o] = g[o]/||v[o]|| * v[o][c][j]
__global__ void wn_kernel(const float* __restrict__ v1, const float* __restrict__ g1,
                          const float* __restrict__ v2, const float* __restrict__ g2,
                          float* __restrict__ w1t, float* __restrict__ w2t) {
    const float* v = (blockIdx.x == 0) ? v1 : v2;
    const float* g = (blockIdx.x == 0) ? g1 : g2;
    float* wt      = (blockIdx.x == 0) ? w1t : w2t;
    int o = threadIdx.x;
    const float* row = v + (size_t)o * 768;
    float s = 0.f;
    for (int i = 0; i < 768; ++i) { float t = row[i]; s += t * t; }
    float scale = g[o] * rsqrtf(s);
    for (int c = 0; c < 256; ++c)
        for (int j = 0; j < 3; ++j)
            wt[j * 65536 + c * 256 + o] = scale * row[c * 3 + j];
}

// ---------------------------------------------------------------------------
// QKV: out[b,t,:] = x[b,:,t]^T @ W + bias. One block = 64 t x 64 n tile.
__global__ __launch_bounds__(256, 4)
void qkv_kernel(const float* __restrict__ x,
                const float* __restrict__ wq, const float* __restrict__ bq,
                const float* __restrict__ wk, const float* __restrict__ bk,
                const float* __restrict__ wv, const float* __restrict__ bv,
                float* __restrict__ qb, float* __restrict__ kb, float* __restrict__ vb) {
    __shared__ float Al[64 * 68];   // [c][t]
    __shared__ float Bl[64 * 68];   // [c][n]
    int tid = threadIdx.x;
    int gx = blockIdx.x;            // b*16 + ttile
    int b = gx >> 4, t0 = (gx & 15) * 64;
    int n0 = blockIdx.y * 64;       // 0..383

    const float* wbase; const float* bias; float* outp; int ldw, ldo, nb;
    if (n0 < 64)       { wbase = wq; bias = bq; outp = qb; ldw = 64;  ldo = 64;  nb = n0; }
    else if (n0 < 128) { wbase = wk; bias = bk; outp = kb; ldw = 64;  ldo = 64;  nb = n0 - 64; }
    else               { wbase = wv; bias = bv; outp = vb; ldw = 256; ldo = 256; nb = n0 - 128; }

    int rg = tid & 15, og = tid >> 4;
    float acc[4][4];
    for (int j = 0; j < 4; ++j) {
        float bj = bias[nb + 4 * og + j];
        for (int i = 0; i < 4; ++i) acc[i][j] = bj;
    }
    int cc = tid >> 2, tseg = (tid & 3) * 16;
    for (int kc = 0; kc < 4; ++kc) {
        int c0 = kc * 64;
        __syncthreads();
        const float* xr = x + ((size_t)b * CC + c0 + cc) * TT + t0 + tseg;
        const float* wr = wbase + (size_t)(c0 + cc) * ldw + nb + tseg;
        for (int i = 0; i < 4; ++i) {
            *reinterpret_cast<f4*>(&Al[cc * 68 + tseg + 4 * i]) = *reinterpret_cast<const f4*>(xr + 4 * i);
            *reinterpret_cast<f4*>(&Bl[cc * 68 + tseg + 4 * i]) = *reinterpret_cast<const f4*>(wr + 4 * i);
        }
        __syncthreads();
        for (int c = 0; c < 64; ++c) {
            f4 a4 = *reinterpret_cast<const f4*>(&Al[c * 68 + 4 * rg]);
            f4 b4 = *reinterpret_cast<const f4*>(&Bl[c * 68 + 4 * og]);
            for (int i = 0; i < 4; ++i)
                for (int j = 0; j < 4; ++j)
                    acc[i][j] += a4[i] * b4[j];
        }
    }
    for (int i = 0; i < 4; ++i) {
        f4 r; for (int j = 0; j < 4; ++j) r[j] = acc[i][j];
        *reinterpret_cast<f4*>(&outp[((size_t)b * TT + t0 + 4 * rg + i) * ldo + nb + 4 * og]) = r;
    }
}

// ---------------------------------------------------------------------------
// Per-key-column softmax stats over the QUERY axis (valid q >= k).
// Block = (b, k-tile of 64). Online (m,Z) merge over q-tiles, then LDS reduce.
__global__ __launch_bounds__(256, 4)
void colstats_kernel(const float* __restrict__ qb, const float* __restrict__ kb,
                     float* __restrict__ colm, float* __restrict__ colrz) {
    __shared__ float Ql[64 * 68];   // [d][q]
    __shared__ float Kl[64 * 68];   // [d][k]
    int tid = threadIdx.x;
    int b = blockIdx.x >> 4, kt = blockIdx.x & 15;
    int k0 = kt * 64;
    int qg = tid >> 4, cg = tid & 15;
    int rl = tid >> 2, seg16 = (tid & 3) * 16;
    {
        const float* kr = kb + ((size_t)b * TT + k0 + rl) * KSZ + seg16;
        for (int i = 0; i < 4; ++i) {
            f4 v = *reinterpret_cast<const f4*>(kr + 4 * i);
            for (int p = 0; p < 4; ++p) Kl[(seg16 + 4 * i + p) * 68 + rl] = v[p];
        }
    }
    float m[4], z[4];
    for (int j = 0; j < 4; ++j) { m[j] = -1e30f; z[j] = 0.f; }

    for (int qt = kt; qt < 16; ++qt) {
        int q0 = qt * 64;
        __syncthreads();
        const float* qr = qb + ((size_t)b * TT + q0 + rl) * KSZ + seg16;
        for (int i = 0; i < 4; ++i) {
            f4 v = *reinterpret_cast<const f4*>(qr + 4 * i);
            for (int p = 0; p < 4; ++p) Ql[(seg16 + 4 * i + p) * 68 + rl] = v[p];
        }
        __syncthreads();
        float s[4][4];
        for (int i = 0; i < 4; ++i) for (int j = 0; j < 4; ++j) s[i][j] = 0.f;
        for (int d = 0; d < 64; ++d) {
            f4 q4 = *reinterpret_cast<const f4*>(&Ql[d * 68 + 4 * qg]);
            f4 k4 = *reinterpret_cast<const f4*>(&Kl[d * 68 + 4 * cg]);
            for (int i = 0; i < 4; ++i)
                for (int j = 0; j < 4; ++j)
                    s[i][j] += q4[i] * k4[j];
        }
        for (int j = 0; j < 4; ++j) {
            int kk = k0 + 4 * cg + j;
            float sv[4]; bool val[4];
            float tmax = -1e30f;
            for (int i = 0; i < 4; ++i) {
                val[i] = (q0 + 4 * qg + i) >= kk;
                sv[i] = s[i][j] * 0.125f;             // 1/sqrt(64)
                if (val[i]) tmax = fmaxf(tmax, sv[i]);
            }
            if (tmax > -1e29f) {
                float nm = fmaxf(m[j], tmax);
                float za = 0.f;
                for (int i = 0; i < 4; ++i) if (val[i]) za += __expf(sv[i] - nm);
                z[j] = z[j] * __expf(m[j] - nm) + za;
                m[j] = nm;
            }
        }
    }
    __syncthreads();
    float* redm = Ql; float* redz = Kl;   // reuse
    for (int j = 0; j < 4; ++j) {
        redm[qg * 68 + 4 * cg + j] = m[j];
        redz[qg * 68 + 4 * cg + j] = z[j];
    }
    __syncthreads();
    if (tid < 64) {
        float mm = -1e30f, zz = 0.f;
        for (int g = 0; g < 16; ++g) {
            float mg = redm[g * 68 + tid], zg = redz[g * 68 + tid];
            if (zg > 0.f) {
                float nm = fmaxf(mm, mg);
                zz = zz * __expf(mm - nm) + zg * __expf(mg - nm);
                mm = nm;
            }
        }
        colm[(size_t)b * TT + k0 + tid] = mm;
        colrz[(size_t)b * TT + k0 + tid] = 1.0f / zz;
    }
}

// ---------------------------------------------------------------------------
// Apply: out_attn[b,q,c] = sum_k p[q,k] * v[k,c];  rowsum[b,q] = sum_k p[q,k].
// Block = (b, q-tile of 64). s recomputed, P staged [k][q], V chunks share K's LDS.
__global__ __launch_bounds__(256, 3)
void attn_kernel(const float* __restrict__ qb, const float* __restrict__ kb,
                 const float* __restrict__ vb, const float* __restrict__ colm,
                 const float* __restrict__ colrz, float* __restrict__ oa,
                 float* __restrict__ rowsum) {
    __shared__ float Ql[64 * 68];   // [d][q]
    __shared__ float KV[64 * 68];   // [d][k] then [k][c]
    __shared__ float Pl[64 * 68];   // [k][q]
    int tid = threadIdx.x;
    int b = blockIdx.x >> 4, qt = blockIdx.x & 15;
    int t0 = qt * 64;
    int qg = tid >> 4, cg = tid & 15;   // step A: rows=q(4qg..), cols=k(4cg..)
    int rgb = tid & 15, ogb = tid >> 4; // step B: rows=q(4rgb..), cols=c(4ogb..)
    int rl = tid >> 2, seg16 = (tid & 3) * 16;
    {
        const float* qr = qb + ((size_t)b * TT + t0 + rl) * KSZ + seg16;
        for (int i = 0; i < 4; ++i) {
            f4 v = *reinterpret_cast<const f4*>(qr + 4 * i);
            for (int p = 0; p < 4; ++p) Ql[(seg16 + 4 * i + p) * 68 + rl] = v[p];
        }
    }
    float acc[4][4][4];  // [i(q)][ch][j(c)]
    for (int i = 0; i < 4; ++i) for (int c = 0; c < 4; ++c) for (int j = 0; j < 4; ++j) acc[i][c][j] = 0.f;
    float rsum[4] = {0.f, 0.f, 0.f, 0.f};

    for (int kt = 0; kt <= qt; ++kt) {
        int k0 = kt * 64;
        __syncthreads();
        const float* kr = kb + ((size_t)b * TT + k0 + rl) * KSZ + seg16;
        for (int i = 0; i < 4; ++i) {
            f4 v = *reinterpret_cast<const f4*>(kr + 4 * i);
            for (int p = 0; p < 4; ++p) KV[(seg16 + 4 * i + p) * 68 + rl] = v[p];
        }
        float cm[4], crz[4];
        for (int j = 0; j < 4; ++j) {
            cm[j]  = colm[(size_t)b * TT + k0 + 4 * cg + j];
            crz[j] = colrz[(size_t)b * TT + k0 + 4 * cg + j];
        }
        __syncthreads();
        float s[4][4];
        for (int i = 0; i < 4; ++i) for (int j = 0; j < 4; ++j) s[i][j] = 0.f;
        for (int d = 0; d < 64; ++d) {
            f4 q4 = *reinterpret_cast<const f4*>(&Ql[d * 68 + 4 * qg]);
            f4 k4 = *reinterpret_cast<const f4*>(&KV[d * 68 + 4 * cg]);
            for (int i = 0; i < 4; ++i)
                for (int j = 0; j < 4; ++j)
                    s[i][j] += q4[i] * k4[j];
        }
        for (int j = 0; j < 4; ++j) {
            int kk = k0 + 4 * cg + j;
            for (int i = 0; i < 4; ++i) {
                int qq = t0 + 4 * qg + i;
                float p = (qq >= kk) ? __expf(s[i][j] * 0.125f - cm[j]) * crz[j] : 0.f;
                rsum[i] += p;
                Pl[(4 * cg + j) * 68 + 4 * qg + i] = p;
            }
        }
        __syncthreads();
        for (int ch = 0; ch < 4; ++ch) {
            const float* vr = vb + ((size_t)b * TT + k0 + rl) * CC + ch * 64 + seg16;
            for (int i = 0; i < 4; ++i)
                *reinterpret_cast<f4*>(&KV[rl * 68 + seg16 + 4 * i]) = *reinterpret_cast<const f4*>(vr + 4 * i);
            __syncthreads();
            for (int k = 0; k < 64; ++k) {
                f4 p4 = *reinterpret_cast<const f4*>(&Pl[k * 68 + 4 * rgb]);
                f4 v4 = *reinterpret_cast<const f4*>(&KV[k * 68 + 4 * ogb]);
                for (int i = 0; i < 4; ++i)
                    for (int j = 0; j < 4; ++j)
                        acc[i][ch][j] += p4[i] * v4[j];
            }
            __syncthreads();
        }
    }
    // rowsum reduction (reuse Ql)
    for (int i = 0; i < 4; ++i) Ql[cg * 68 + 4 * qg + i] = rsum[i];
    __syncthreads();
    if (tid < 64) {
        float s = 0.f;
        for (int g = 0; g < 16; ++g) s += Ql[g * 68 + tid];
        rowsum[(size_t)b * TT + t0 + tid] = s;
    }
    for (int ch = 0; ch < 4; ++ch)
        for (int i = 0; i < 4; ++i) {
            f4 r; for (int j = 0; j < 4; ++j) r[j] = acc[i][ch][j];
            *reinterpret_cast<f4*>(&oa[((size_t)b * TT + t0 + 4 * rgb + i) * CC + ch * 64 + 4 * ogb]) = r;
        }
}

// ---------------------------------------------------------------------------
// Causal K=3 conv as 3-tap GEMM: out[b,t,o] = relu(bias[o] + sum_{c,j} in[b,t-2+j,c]*W[j][c][o])
__global__ __launch_bounds__(256, 4)
void conv_kernel(const float* __restrict__ in, const float* __restrict__ wt,
                 const float* __restrict__ bias, float* __restrict__ out) {
    __shared__ float Al[32 * 68];       // [c][t] with 2-row halo: col tl <-> t0+tl-2
    __shared__ float Bw[3 * 32 * 68];   // [j][c][o]
    int tid = threadIdx.x;
    int o0 = blockIdx.x * 64, t0 = blockIdx.y * 64, b = blockIdx.z;
    int rg = tid & 15, og = tid >> 4;
    float acc[4][4];
    for (int i = 0; i < 4; ++i) for (int j = 0; j < 4; ++j) acc[i][j] = 0.f;
    int tl = tid >> 2, cq = tid & 3;
    int ccB = tid >> 3, oseg = (tid & 7) * 8;

    for (int kc = 0; kc < 8; ++kc) {
        int c0 = kc * 32;
        __syncthreads();
        for (int pass = 0; pass < 2; ++pass) {
            int tll = tl + pass * 64;
            if (tll < 66) {
                int t = t0 + tll - 2;
                for (int s2 = 0; s2 < 2; ++s2) {
                    int c = cq * 8 + 4 * s2;
                    f4 v;
                    if (t >= 0) v = *reinterpret_cast<const f4*>(&in[((size_t)b * TT + t) * CC + c0 + c]);
                    else { v[0] = 0.f; v[1] = 0.f; v[2] = 0.f; v[3] = 0.f; }
                    for (int p = 0; p < 4; ++p) Al[(c + p) * 68 + tll] = v[p];
                }
            }
        }
        for (int j = 0; j < 3; ++j) {
            const float* wr = wt + j * 65536 + (size_t)(c0 + ccB) * 256 + o0 + oseg;
            for (int s2 = 0; s2 < 2; ++s2)
                *reinterpret_cast<f4*>(&Bw[j * 2176 + ccB * 68 + oseg + 4 * s2]) =
                    *reinterpret_cast<const f4*>(wr + 4 * s2);
        }
        __syncthreads();
        for (int j = 0; j < 3; ++j)
            for (int c = 0; c < 32; ++c) {
                f4 w4 = *reinterpret_cast<const f4*>(&Bw[j * 2176 + c * 68 + 4 * og]);
                float a_[4];
                for (int i = 0; i < 4; ++i) a_[i] = Al[c * 68 + 4 * rg + i + j];
                for (int i = 0; i < 4; ++i)
                    for (int jj = 0; jj < 4; ++jj)
                        acc[i][jj] += a_[i] * w4[jj];
            }
    }
    for (int i = 0; i < 4; ++i) {
        f4 r;
        for (int jj = 0; jj < 4; ++jj) r[jj] = fmaxf(acc[i][jj] + bias[o0 + 4 * og + jj], 0.f);
        *reinterpret_cast<f4*>(&out[((size_t)b * TT + t0 + 4 * rg + i) * CC + o0 + 4 * og]) = r;
    }
}

// ---------------------------------------------------------------------------
// weight_x[b,:] = softmax over t of rowsum[b,:]
__global__ void rowsm_kernel(const float* __restrict__ rowsum, float* __restrict__ wx) {
    __shared__ float red[256];
    int b = blockIdx.x, tid = threadIdx.x;
    float v[4];
    float m = -1e30f;
    for (int r = 0; r < 4; ++r) { v[r] = rowsum[(size_t)b * TT + tid + 256 * r]; m = fmaxf(m, v[r]); }
    red[tid] = m; __syncthreads();
    for (int s = 128; s > 0; s >>= 1) { if (tid < s) red[tid] = fmaxf(red[tid], red[tid + s]); __syncthreads(); }
    m = red[0]; __syncthreads();
    float e[4], zs = 0.f;
    for (int r = 0; r < 4; ++r) { e[r] = __expf(v[r] - m); zs += e[r]; }
    red[tid] = zs; __syncthreads();
    for (int s = 128; s > 0; s >>= 1) { if (tid < s) red[tid] += red[tid + s]; __syncthreads(); }
    float rz = 1.0f / red[0];
    for (int r = 0; r < 4; ++r) wx[(size_t)b * TT + tid + 256 * r] = e[r] * rz;
}

// ---------------------------------------------------------------------------
// out[b,c,t] = relu(c2[b,t,c] + x[b,c,t]*(1 + wx[b,t]))  via 32x32 LDS transpose
__global__ void final_kernel(const float* __restrict__ c2, const float* __restrict__ x,
                             const float* __restrict__ wx, float* __restrict__ out) {
    __shared__ float tile[32 * 33];
    int tid = threadIdx.x;
    int c0 = blockIdx.x * 32, t0 = blockIdx.y * 32, b = blockIdx.z;
    int tl = tid >> 3, c4 = (tid & 7) * 4;
    f4 v = *reinterpret_cast<const f4*>(&c2[((size_t)b * TT + t0 + tl) * CC + c0 + c4]);
    for (int p = 0; p < 4; ++p) tile[tl * 33 + c4 + p] = v[p];
    __syncthreads();
    int cl = tid >> 3, t4 = (tid & 7) * 4;
    f4 x4 = *reinterpret_cast<const f4*>(&x[((size_t)b * CC + c0 + cl) * TT + t0 + t4]);
    f4 w4 = *reinterpret_cast<const f4*>(&wx[(size_t)b * TT + t0 + t4]);
    f4 r;
    for (int p = 0; p < 4; ++p) {
        float cv = tile[(t4 + p) * 33 + cl];
        r[p] = fmaxf(cv + x4[p] * (1.f + w4[p]), 0.f);
    }
    *reinterpret_cast<f4*>(&out[((size_t)b * CC + c0 + cl) * TT + t0 + t4]) = r;
}

// ---------------------------------------------------------------------------
extern "C" void kernel_launch(void* const* d_in, const int* in_sizes, int n_in,
                              void* d_out, int out_size, void* d_ws, size_t ws_size,
                              hipStream_t stream) {
    (void)in_sizes; (void)n_in; (void)out_size; (void)ws_size;
    const float* x  = (const float*)d_in[0];
    const float* wq = (const float*)d_in[1];
    const float* bq = (const float*)d_in[2];
    const float* wk = (const float*)d_in[3];
    const float* bk = (const float*)d_in[4];
    const float* wv = (const float*)d_in[5];
    const float* bv = (const float*)d_in[6];
    const float* v1 = (const float*)d_in[7];
    const float* g1 = (const float*)d_in[8];
    const float* b1 = (const float*)d_in[9];
    const float* v2 = (const float*)d_in[10];
    const float* g2 = (const float*)d_in[11];
    const float* b2 = (const float*)d_in[12];
    float* ws  = (float*)d_ws;
    float* out = (float*)d_out;

    float* qb   = ws + OFF_Q;
    float* kb   = ws + OFF_K;
    float* vbuf = ws + OFF_V;    // later: conv1 output c1
    float* oab  = ws + OFF_OA;   // later: conv2 output c2
    float* cm   = ws + OFF_CM;
    float* crz  = ws + OFF_CR;
    float* rs   = ws + OFF_RS;
    float* wxb  = ws + OFF_WX;
    float* w1   = ws + OFF_W1;
    float* w2   = ws + OFF_W2;

    wn_kernel<<<dim3(2), dim3(256), 0, stream>>>(v1, g1, v2, g2, w1, w2);
    qkv_kernel<<<dim3(512, 6), dim3(256), 0, stream>>>(x, wq, bq, wk, bk, wv, bv, qb, kb, vbuf);
    colstats_kernel<<<dim3(512), dim3(256), 0, stream>>>(qb, kb, cm, crz);
    attn_kernel<<<dim3(512), dim3(256), 0, stream>>>(qb, kb, vbuf, cm, crz, oab, rs);
    conv_kernel<<<dim3(4, 16, 32), dim3(256), 0, stream>>>(oab, w1, b1, vbuf);   // c1 -> vbuf
    conv_kernel<<<dim3(4, 16, 32), dim3(256), 0, stream>>>(vbuf, w2, b2, oab);   // c2 -> oab
    rowsm_kernel<<<dim3(32), dim3(256), 0, stream>>>(rs, wxb);
    final_kernel<<<dim3(8, 32, 32), dim3(256), 0, stream>>>(oab, x, wxb, out);
}

// Round 3
// 370.639 us; speedup vs baseline: 3.0857x; 3.0857x over previous
//
#include <hip/hip_runtime.h>
#include <math.h>

#define BB 32
#define CC 256
#define TT 1024

typedef __attribute__((ext_vector_type(4))) float f4;
typedef __attribute__((ext_vector_type(4))) float f32x4;
typedef __attribute__((ext_vector_type(8))) short s8;   // bf16x8 MFMA frag (4 VGPRs)
typedef __attribute__((ext_vector_type(4))) short s4v;  // 8B LDS store

__device__ inline short f2bf(float f) {                 // RNE fp32->bf16
    unsigned u = __builtin_bit_cast(unsigned, f);
    u = (u + 0x7FFFu + ((u >> 16) & 1u)) >> 16;
    return (short)u;
}

// ---- workspace layout (bytes) ----  total 76,873,728 B = 73.3 MB
// R2 bug: W1/W2/WQKV were spaced at HALF their sizes -> overlapped (absmax 1.3).
static const size_t OFF_QBF  = 0;          // [B][T][64] bf16   4 MB
static const size_t OFF_KBF  = 4194304;    // [B][T][64] bf16   4 MB
static const size_t OFF_VT   = 8388608;    // [B][C][T]  bf16  16 MB (v transposed)
static const size_t OFF_OA   = 25165824;   // [B][T][C]  fp32  32 MB (out_attn; later c2; first 16MB also xt)
static const size_t OFF_C1   = 58720256;   // [B][T][C]  bf16  16 MB (conv1 out)
static const size_t OFF_CRZ  = 75497472;   // [B][T] fp32 col 1/Z          (131072 B)
static const size_t OFF_RS   = 75628544;   // [B][T] fp32 rowsum           (131072 B)
static const size_t OFF_WX   = 75759616;   // [B][T] fp32 weight_x         (131072 B)
static const size_t OFF_W1   = 75890688;   // [3][256][256] bf16 W1 [j][o][c]  (393216 B)
static const size_t OFF_W2   = 76283904;   // [3][256][256] bf16 W2            (393216 B)
static const size_t OFF_WQKV = 76677120;   // [384][256] bf16 (q|k|v) [n][c]   (196608 B)

// ---------------------------------------------------------------------------
// prep: weight-norm conv weights -> bf16 [j][o][c]; pack wq|wk|wv -> bf16 [n][c]
__global__ void prep_kernel(const float* __restrict__ v1, const float* __restrict__ g1,
                            const float* __restrict__ v2, const float* __restrict__ g2,
                            const float* __restrict__ wq, const float* __restrict__ wk,
                            const float* __restrict__ wv,
                            short* __restrict__ w1bf, short* __restrict__ w2bf,
                            short* __restrict__ wqkvbf) {
    int bx = blockIdx.x, tid = threadIdx.x;
    if (bx < 2) {
        const float* v = bx ? v2 : v1;
        const float* g = bx ? g2 : g1;
        short* wt = bx ? w2bf : w1bf;
        const float* row = v + (size_t)tid * 768;
        float s = 0.f;
        for (int i = 0; i < 768; ++i) s += row[i] * row[i];
        float scale = g[tid] * rsqrtf(s);
        for (int c = 0; c < 256; ++c)
            for (int j = 0; j < 3; ++j)
                wt[((size_t)j * 256 + tid) * 256 + c] = f2bf(scale * row[c * 3 + j]);
    } else {
        int n = (bx - 2) * 64 + (tid >> 2);
        int c0 = (tid & 3) * 64;
        for (int cc = 0; cc < 64; ++cc) {
            int c = c0 + cc;
            float w;
            if (n < 64)       w = wq[c * 64 + n];
            else if (n < 128) w = wk[c * 64 + n - 64];
            else              w = wv[c * 256 + n - 128];
            wqkvbf[(size_t)n * 256 + c] = f2bf(w);
        }
    }
}

// ---------------------------------------------------------------------------
// x [b][c][t] fp32 -> xt [b][t][c] bf16  (64x64 tiles)
__global__ void transpose_kernel(const float* __restrict__ x, short* __restrict__ xt) {
    __shared__ float Tt[64 * 68];
    int tid = threadIdx.x;
    int c0 = blockIdx.x * 64, t0 = blockIdx.y * 64, b = blockIdx.z;
    for (int it = 0; it < 4; ++it) {
        int idx = tid + 256 * it;
        int cr = idx >> 4, tc = idx & 15;
        f4 v = *reinterpret_cast<const f4*>(&x[((size_t)b * CC + c0 + cr) * TT + t0 + tc * 4]);
        *reinterpret_cast<f4*>(&Tt[cr * 68 + tc * 4]) = v;
    }
    __syncthreads();
    for (int it = 0; it < 2; ++it) {
        int idx = tid + 256 * it;
        int tl = idx >> 3, seg = idx & 7;
        s8 o;
        for (int p = 0; p < 8; ++p) o[p] = f2bf(Tt[(seg * 8 + p) * 68 + tl]);
        *reinterpret_cast<s8*>(&xt[((size_t)b * TT + t0 + tl) * CC + c0 + seg * 8]) = o;
    }
}

// ---------------------------------------------------------------------------
// QKV GEMM: xt[b][t][c] bf16 @ wqkv[n][c] -> q/k bf16 [t][64], v -> vt bf16 [c][t]
__global__ __launch_bounds__(256, 3)
void qkv_kernel(const short* __restrict__ xt, const short* __restrict__ wqkv,
                const float* __restrict__ bq, const float* __restrict__ bk,
                const float* __restrict__ bv,
                short* __restrict__ qbf, short* __restrict__ kbf, short* __restrict__ vt) {
    __shared__ short SL[128 * 72 + 64 * 72];   // A (128t x 64c) then B (64n x 64c)
    short* Asm = SL;
    short* Bsm = SL + 128 * 72;
    int tid = threadIdx.x, wv_ = tid >> 6, lane = tid & 63;
    int n15 = lane & 15, quad = lane >> 4;
    int b = blockIdx.x >> 3, t0 = (blockIdx.x & 7) * 128;
    int n0 = blockIdx.y * 64;

    f32x4 acc[2][4];
    for (int i = 0; i < 2; ++i) for (int j = 0; j < 4; ++j)
        for (int p = 0; p < 4; ++p) acc[i][j][p] = 0.f;

    for (int kc = 0; kc < 4; ++kc) {
        int c0 = kc * 64;
        __syncthreads();
        for (int it = 0; it < 4; ++it) {           // A: 128 rows x 8 segs
            int idx = tid + 256 * it;
            int row = idx >> 3, seg = idx & 7;
            *reinterpret_cast<s8*>(&Asm[row * 72 + seg * 8]) =
                *reinterpret_cast<const s8*>(&xt[((size_t)b * TT + t0 + row) * CC + c0 + seg * 8]);
        }
        for (int it = 0; it < 2; ++it) {           // B: 64 rows x 8 segs
            int idx = tid + 256 * it;
            int row = idx >> 3, seg = idx & 7;
            *reinterpret_cast<s8*>(&Bsm[row * 72 + seg * 8]) =
                *reinterpret_cast<const s8*>(&wqkv[(size_t)(n0 + row) * 256 + c0 + seg * 8]);
        }
        __syncthreads();
        for (int ks = 0; ks < 2; ++ks)
            for (int mt2 = 0; mt2 < 2; ++mt2) {
                s8 a = *reinterpret_cast<const s8*>(&Asm[(wv_ * 32 + mt2 * 16 + n15) * 72 + quad * 8 + ks * 32]);
                for (int nt = 0; nt < 4; ++nt) {
                    s8 bb = *reinterpret_cast<const s8*>(&Bsm[(nt * 16 + n15) * 72 + quad * 8 + ks * 32]);
                    acc[mt2][nt] = __builtin_amdgcn_mfma_f32_16x16x32_bf16(a, bb, acc[mt2][nt], 0, 0, 0);
                }
            }
    }
    if (n0 < 128) {
        short* outp = (n0 == 0) ? qbf : kbf;
        const float* bias = (n0 == 0) ? bq : bk;
        for (int mt2 = 0; mt2 < 2; ++mt2)
            for (int nt = 0; nt < 4; ++nt) {
                int n_ = nt * 16 + n15;
                float bvl = bias[n_];
                for (int reg = 0; reg < 4; ++reg) {
                    int t = t0 + wv_ * 32 + mt2 * 16 + quad * 4 + reg;
                    outp[((size_t)b * TT + t) * 64 + n_] = f2bf(acc[mt2][nt][reg] + bvl);
                }
            }
    } else {
        int cbase = n0 - 128;
        __syncthreads();                           // reuse A/B LDS as transpose buffers
        short* Tw = SL + wv_ * 3072;               // per-wave 64n x 48(pad: 32 used)
        for (int mt2 = 0; mt2 < 2; ++mt2)
            for (int nt = 0; nt < 4; ++nt) {
                int n_ = nt * 16 + n15;
                float bvl = bv[cbase + n_];
                for (int reg = 0; reg < 4; ++reg)
                    Tw[n_ * 48 + mt2 * 16 + quad * 4 + reg] = f2bf(acc[mt2][nt][reg] + bvl);
            }
        for (int p = 0; p < 4; ++p) {              // wave-local RAW: lgkmcnt-ordered
            int n_ = (lane >> 2) + 16 * p;
            int seg = lane & 3;
            s8 vv = *reinterpret_cast<const s8*>(&Tw[n_ * 48 + seg * 8]);
            *reinterpret_cast<s8*>(&vt[((size_t)b * CC + cbase + n_) * TT + t0 + wv_ * 32 + seg * 8]) = vv;
        }
    }
}

// ---------------------------------------------------------------------------
// Per-key-column sum of exp(s/8) over q>=k (softmax over QUERY axis; no max
// subtraction needed: |s/8| bounded ~5). Writes 1/Z.
__global__ __launch_bounds__(256, 3)
void colz_kernel(const short* __restrict__ qbf, const short* __restrict__ kbf,
                 float* __restrict__ colrz) {
    __shared__ short Qs[64 * 72], Ks[64 * 72];
    __shared__ float red[4 * 64];
    int tid = threadIdx.x, wv_ = tid >> 6, lane = tid & 63;
    int n15 = lane & 15, quad = lane >> 4;
    int b = blockIdx.x >> 4, kt = blockIdx.x & 15;
    {
        int row = tid >> 2;
        for (int it = 0; it < 2; ++it) {
            int seg = (tid & 3) + 4 * it;
            *reinterpret_cast<s8*>(&Ks[row * 72 + seg * 8]) =
                *reinterpret_cast<const s8*>(&kbf[((size_t)b * TT + kt * 64 + row) * 64 + seg * 8]);
        }
    }
    float z[4] = {0.f, 0.f, 0.f, 0.f};
    for (int qt = kt; qt < 16; ++qt) {
        __syncthreads();
        {
            int row = tid >> 2;
            for (int it = 0; it < 2; ++it) {
                int seg = (tid & 3) + 4 * it;
                *reinterpret_cast<s8*>(&Qs[row * 72 + seg * 8]) =
                    *reinterpret_cast<const s8*>(&qbf[((size_t)b * TT + qt * 64 + row) * 64 + seg * 8]);
            }
        }
        __syncthreads();
        for (int nt = 0; nt < 4; ++nt) {
            f32x4 s;
            for (int p = 0; p < 4; ++p) s[p] = 0.f;
            for (int ks = 0; ks < 2; ++ks) {
                s8 a  = *reinterpret_cast<const s8*>(&Qs[(wv_ * 16 + n15) * 72 + quad * 8 + ks * 32]);
                s8 bb = *reinterpret_cast<const s8*>(&Ks[(nt * 16 + n15) * 72 + quad * 8 + ks * 32]);
                s = __builtin_amdgcn_mfma_f32_16x16x32_bf16(a, bb, s, 0, 0, 0);
            }
            int kg = kt * 64 + nt * 16 + n15;
            int qbase = qt * 64 + wv_ * 16 + quad * 4;
            if (qt > kt) {
                for (int reg = 0; reg < 4; ++reg) z[nt] += __expf(s[reg] * 0.125f);
            } else {
                for (int reg = 0; reg < 4; ++reg)
                    if (qbase + reg >= kg) z[nt] += __expf(s[reg] * 0.125f);
            }
        }
    }
    for (int nt = 0; nt < 4; ++nt) {
        z[nt] += __shfl_xor(z[nt], 16, 64);
        z[nt] += __shfl_xor(z[nt], 32, 64);
    }
    if (lane < 16)
        for (int nt = 0; nt < 4; ++nt) red[wv_ * 64 + nt * 16 + lane] = z[nt];
    __syncthreads();
    if (tid < 64) {
        float Z = red[tid] + red[64 + tid] + red[128 + tid] + red[192 + tid];
        colrz[(size_t)b * TT + kt * 64 + tid] = 1.0f / Z;
    }
}

// ---------------------------------------------------------------------------
// Attention apply: p = exp(s/8)*rz[k] (q>=k), out_attn += P @ V (MFMA),
// rowsum = sum_k p. Grid (b*16+qt', ch); big qt first for balance.
__global__ __launch_bounds__(256, 3)
void attn_kernel(const short* __restrict__ qbf, const short* __restrict__ kbf,
                 const short* __restrict__ vt, const float* __restrict__ colrz,
                 float* __restrict__ oa, float* __restrict__ rowsum) {
    __shared__ short Qs[64 * 72];
    __shared__ short Ks[64 * 72];
    __shared__ short Ps[64 * 72];   // [q][k] bf16 = PV A-operand
    __shared__ short Vs[128 * 72];  // [c][t_k] bf16 = PV B-operand
    __shared__ float redR[64];
    int tid = threadIdx.x, wv_ = tid >> 6, lane = tid & 63;
    int n15 = lane & 15, quad = lane >> 4;
    int b = blockIdx.x >> 4, qt = 15 - (blockIdx.x & 15);   // big tiles first
    int ch = blockIdx.y;
    {
        int row = tid >> 2;
        for (int it = 0; it < 2; ++it) {
            int seg = (tid & 3) + 4 * it;
            *reinterpret_cast<s8*>(&Qs[row * 72 + seg * 8]) =
                *reinterpret_cast<const s8*>(&qbf[((size_t)b * TT + qt * 64 + row) * 64 + seg * 8]);
        }
    }
    f32x4 acc[8];
    for (int i = 0; i < 8; ++i) for (int p = 0; p < 4; ++p) acc[i][p] = 0.f;
    float rsum[4] = {0.f, 0.f, 0.f, 0.f};

    for (int kt = 0; kt <= qt; ++kt) {
        __syncthreads();
        {
            int row = tid >> 2;
            for (int it = 0; it < 2; ++it) {
                int seg = (tid & 3) + 4 * it;
                *reinterpret_cast<s8*>(&Ks[row * 72 + seg * 8]) =
                    *reinterpret_cast<const s8*>(&kbf[((size_t)b * TT + kt * 64 + row) * 64 + seg * 8]);
            }
        }
        for (int it = 0; it < 4; ++it) {
            int idx = tid + 256 * it;
            int row = idx >> 3, seg = idx & 7;
            *reinterpret_cast<s8*>(&Vs[row * 72 + seg * 8]) =
                *reinterpret_cast<const s8*>(&vt[((size_t)b * CC + ch * 128 + row) * TT + kt * 64 + seg * 8]);
        }
        __syncthreads();
        // scores -> p -> Ps (each wave touches only its own 16 q rows of Ps)
        for (int nt = 0; nt < 4; ++nt) {
            f32x4 s;
            for (int p = 0; p < 4; ++p) s[p] = 0.f;
            for (int ks = 0; ks < 2; ++ks) {
                s8 a  = *reinterpret_cast<const s8*>(&Qs[(wv_ * 16 + n15) * 72 + quad * 8 + ks * 32]);
                s8 bb = *reinterpret_cast<const s8*>(&Ks[(nt * 16 + n15) * 72 + quad * 8 + ks * 32]);
                s = __builtin_amdgcn_mfma_f32_16x16x32_bf16(a, bb, s, 0, 0, 0);
            }
            int kg = kt * 64 + nt * 16 + n15;
            float rz = colrz[(size_t)b * TT + kg];
            int qbase = qt * 64 + wv_ * 16 + quad * 4;
            for (int reg = 0; reg < 4; ++reg) {
                float p = 0.f;
                if (kt < qt || qbase + reg >= kg) p = __expf(s[reg] * 0.125f) * rz;
                rsum[reg] += p;
                Ps[(wv_ * 16 + quad * 4 + reg) * 72 + nt * 16 + n15] = f2bf(p);
            }
        }
        // PV: Ps rows are wave-private (lgkmcnt-ordered), Vs covered by barrier
        for (int ks = 0; ks < 2; ++ks) {
            s8 a = *reinterpret_cast<const s8*>(&Ps[(wv_ * 16 + n15) * 72 + quad * 8 + ks * 32]);
            for (int nt = 0; nt < 8; ++nt) {
                s8 bb = *reinterpret_cast<const s8*>(&Vs[(nt * 16 + n15) * 72 + quad * 8 + ks * 32]);
                acc[nt] = __builtin_amdgcn_mfma_f32_16x16x32_bf16(a, bb, acc[nt], 0, 0, 0);
            }
        }
    }
    if (ch == 0) {
        for (int reg = 0; reg < 4; ++reg) {
            float v = rsum[reg];
            v += __shfl_xor(v, 1, 64);
            v += __shfl_xor(v, 2, 64);
            v += __shfl_xor(v, 4, 64);
            v += __shfl_xor(v, 8, 64);
            if (n15 == 0) redR[wv_ * 16 + quad * 4 + reg] = v;
        }
    }
    for (int nt = 0; nt < 8; ++nt) {
        int c = ch * 128 + nt * 16 + n15;
        for (int reg = 0; reg < 4; ++reg) {
            int q = qt * 64 + wv_ * 16 + quad * 4 + reg;
            oa[((size_t)b * TT + q) * CC + c] = acc[nt][reg];
        }
    }
    if (ch == 0) {
        __syncthreads();
        if (tid < 64) rowsum[(size_t)b * TT + qt * 64 + tid] = redR[tid];
    }
}

// ---------------------------------------------------------------------------
// Causal K=3 conv as MFMA GEMM: out[t,o] = relu(b[o] + sum_{j,c} in[t-2+j,c]*W[j][o][c])
// A tile: 130-row halo [t][c]; B: [j][o][c]. Block 128t x 64o.
__global__ __launch_bounds__(256, 3)
void conv_kernel(const void* __restrict__ inp, int in_is_fp32,
                 const short* __restrict__ wbf, const float* __restrict__ bias,
                 void* __restrict__ outp, int out_is_bf16) {
    __shared__ short As[130 * 72];
    __shared__ short Bs[3 * 64 * 72];
    int tid = threadIdx.x, wv_ = tid >> 6, lane = tid & 63;
    int n15 = lane & 15, quad = lane >> 4;
    int b = blockIdx.x >> 3, mt = blockIdx.x & 7;
    int n0 = blockIdx.y * 64;
    int t0 = mt * 128;
    f32x4 acc[2][4];
    for (int i = 0; i < 2; ++i) for (int j = 0; j < 4; ++j)
        for (int p = 0; p < 4; ++p) acc[i][j][p] = 0.f;

    for (int kc = 0; kc < 4; ++kc) {
        int c0 = kc * 64;
        __syncthreads();
        if (in_is_fp32) {
            const float* in = (const float*)inp;
            for (int it = 0; it < 9; ++it) {
                int idx = tid + 256 * it;
                int row = idx >> 4, fc = idx & 15;
                if (row < 130) {
                    int t = t0 + row - 2;
                    s4v st;
                    if (t >= 0) {
                        f4 v = *reinterpret_cast<const f4*>(&in[((size_t)b * TT + t) * CC + c0 + fc * 4]);
                        for (int p = 0; p < 4; ++p) st[p] = f2bf(v[p]);
                    } else { for (int p = 0; p < 4; ++p) st[p] = 0; }
                    *reinterpret_cast<s4v*>(&As[row * 72 + fc * 4]) = st;
                }
            }
        } else {
            const short* in = (const short*)inp;
            for (int it = 0; it < 5; ++it) {
                int idx = tid + 256 * it;
                int row = idx >> 3, seg = idx & 7;
                if (row < 130) {
                    int t = t0 + row - 2;
                    s8 st;
                    if (t >= 0) st = *reinterpret_cast<const s8*>(&in[((size_t)b * TT + t) * CC + c0 + seg * 8]);
                    else for (int p = 0; p < 8; ++p) st[p] = 0;
                    *reinterpret_cast<s8*>(&As[row * 72 + seg * 8]) = st;
                }
            }
        }
        for (int it = 0; it < 6; ++it) {     // B: 192 rows (j,o) x 8 segs
            int idx = tid + 256 * it;
            int row = idx >> 3, seg = idx & 7;
            int j = row >> 6, o = row & 63;
            *reinterpret_cast<s8*>(&Bs[row * 72 + seg * 8]) =
                *reinterpret_cast<const s8*>(&wbf[((size_t)(j * 256 + n0 + o)) * 256 + c0 + seg * 8]);
        }
        __syncthreads();
        for (int j = 0; j < 3; ++j)
            for (int ks = 0; ks < 2; ++ks)
                for (int mt2 = 0; mt2 < 2; ++mt2) {
                    s8 a = *reinterpret_cast<const s8*>(&As[(wv_ * 32 + mt2 * 16 + n15 + j) * 72 + quad * 8 + ks * 32]);
                    for (int nt = 0; nt < 4; ++nt) {
                        s8 bb = *reinterpret_cast<const s8*>(&Bs[(j * 64 + nt * 16 + n15) * 72 + quad * 8 + ks * 32]);
                        acc[mt2][nt] = __builtin_amdgcn_mfma_f32_16x16x32_bf16(a, bb, acc[mt2][nt], 0, 0, 0);
                    }
                }
    }
    for (int mt2 = 0; mt2 < 2; ++mt2)
        for (int nt = 0; nt < 4; ++nt) {
            int o = n0 + nt * 16 + n15;
            float bvl = bias[o];
            for (int reg = 0; reg < 4; ++reg) {
                int t = t0 + wv_ * 32 + mt2 * 16 + quad * 4 + reg;
                float v = fmaxf(acc[mt2][nt][reg] + bvl, 0.f);
                if (out_is_bf16) ((short*)outp)[((size_t)b * TT + t) * CC + o] = f2bf(v);
                else             ((float*)outp)[((size_t)b * TT + t) * CC + o] = v;
            }
        }
}

// ---------------------------------------------------------------------------
__global__ void rowsm_kernel(const float* __restrict__ rowsum, float* __restrict__ wx) {
    __shared__ float red[256];
    int b = blockIdx.x, tid = threadIdx.x;
    float v[4];
    float m = -1e30f;
    for (int r = 0; r < 4; ++r) { v[r] = rowsum[(size_t)b * TT + tid + 256 * r]; m = fmaxf(m, v[r]); }
    red[tid] = m; __syncthreads();
    for (int s = 128; s > 0; s >>= 1) { if (tid < s) red[tid] = fmaxf(red[tid], red[tid + s]); __syncthreads(); }
    m = red[0]; __syncthreads();
    float e[4], zs = 0.f;
    for (int r = 0; r < 4; ++r) { e[r] = __expf(v[r] - m); zs += e[r]; }
    red[tid] = zs; __syncthreads();
    for (int s = 128; s > 0; s >>= 1) { if (tid < s) red[tid] += red[tid + s]; __syncthreads(); }
    float rz = 1.0f / red[0];
    for (int r = 0; r < 4; ++r) wx[(size_t)b * TT + tid + 256 * r] = e[r] * rz;
}

// ---------------------------------------------------------------------------
__global__ void final_kernel(const float* __restrict__ c2, const float* __restrict__ x,
                             const float* __restrict__ wx, float* __restrict__ out) {
    __shared__ float tile[32 * 33];
    int tid = threadIdx.x;
    int c0 = blockIdx.x * 32, t0 = blockIdx.y * 32, b = blockIdx.z;
    int tl = tid >> 3, c4 = (tid & 7) * 4;
    f4 v = *reinterpret_cast<const f4*>(&c2[((size_t)b * TT + t0 + tl) * CC + c0 + c4]);
    for (int p = 0; p < 4; ++p) tile[tl * 33 + c4 + p] = v[p];
    __syncthreads();
    int cl = tid >> 3, t4 = (tid & 7) * 4;
    f4 x4 = *reinterpret_cast<const f4*>(&x[((size_t)b * CC + c0 + cl) * TT + t0 + t4]);
    f4 w4 = *reinterpret_cast<const f4*>(&wx[(size_t)b * TT + t0 + t4]);
    f4 r;
    for (int p = 0; p < 4; ++p) {
        float cv = tile[(t4 + p) * 33 + cl];
        r[p] = fmaxf(cv + x4[p] * (1.f + w4[p]), 0.f);
    }
    *reinterpret_cast<f4*>(&out[((size_t)b * CC + c0 + cl) * TT + t0 + t4]) = r;
}

// ---------------------------------------------------------------------------
extern "C" void kernel_launch(void* const* d_in, const int* in_sizes, int n_in,
                              void* d_out, int out_size, void* d_ws, size_t ws_size,
                              hipStream_t stream) {
    (void)in_sizes; (void)n_in; (void)out_size; (void)ws_size;
    const float* x  = (const float*)d_in[0];
    const float* wq = (const float*)d_in[1];
    const float* bq = (const float*)d_in[2];
    const float* wk = (const float*)d_in[3];
    const float* bk = (const float*)d_in[4];
    const float* wv = (const float*)d_in[5];
    const float* bv = (const float*)d_in[6];
    const float* v1 = (const float*)d_in[7];
    const float* g1 = (const float*)d_in[8];
    const float* b1 = (const float*)d_in[9];
    const float* v2 = (const float*)d_in[10];
    const float* g2 = (const float*)d_in[11];
    const float* b2 = (const float*)d_in[12];
    char* ws = (char*)d_ws;
    float* out = (float*)d_out;

    short* qbf  = (short*)(ws + OFF_QBF);
    short* kbf  = (short*)(ws + OFF_KBF);
    short* vt   = (short*)(ws + OFF_VT);
    float* oa   = (float*)(ws + OFF_OA);     // out_attn fp32; later c2
    short* xt   = (short*)(ws + OFF_OA);     // xt bf16 (dead before oa written)
    short* c1   = (short*)(ws + OFF_C1);
    float* crz  = (float*)(ws + OFF_CRZ);
    float* rs   = (float*)(ws + OFF_RS);
    float* wxb  = (float*)(ws + OFF_WX);
    short* w1bf = (short*)(ws + OFF_W1);
    short* w2bf = (short*)(ws + OFF_W2);
    short* wqkv = (short*)(ws + OFF_WQKV);

    prep_kernel<<<dim3(8), dim3(256), 0, stream>>>(v1, g1, v2, g2, wq, wk, wv, w1bf, w2bf, wqkv);
    transpose_kernel<<<dim3(4, 16, 32), dim3(256), 0, stream>>>(x, xt);
    qkv_kernel<<<dim3(256, 6), dim3(256), 0, stream>>>(xt, wqkv, bq, bk, bv, qbf, kbf, vt);
    colz_kernel<<<dim3(512), dim3(256), 0, stream>>>(qbf, kbf, crz);
    attn_kernel<<<dim3(512, 2), dim3(256), 0, stream>>>(qbf, kbf, vt, crz, oa, rs);
    conv_kernel<<<dim3(256, 4), dim3(256), 0, stream>>>(oa, 1, w1bf, b1, c1, 1);
    conv_kernel<<<dim3(256, 4), dim3(256), 0, stream>>>(c1, 0, w2bf, b2, oa, 0);
    rowsm_kernel<<<dim3(32), dim3(256), 0, stream>>>(rs, wxb);
    final_kernel<<<dim3(8, 32, 32), dim3(256), 0, stream>>>(oa, x, wxb, out);
}

// Round 4
// 280.058 us; speedup vs baseline: 4.0838x; 1.3234x over previous
//
#include <hip/hip_runtime.h>
#include <math.h>

#define BB 32
#define CC 256
#define TT 1024

typedef __attribute__((ext_vector_type(4))) float f4;
typedef __attribute__((ext_vector_type(4))) float f32x4;
typedef __attribute__((ext_vector_type(8))) short s8;   // bf16x8 MFMA frag (4 VGPRs)
typedef __attribute__((ext_vector_type(4))) short s4v;  // 8B LDS store

__device__ inline short f2bf(float f) {                 // RNE fp32->bf16
    unsigned u = __builtin_bit_cast(unsigned, f);
    u = (u + 0x7FFFu + ((u >> 16) & 1u)) >> 16;
    return (short)u;
}

// ---- workspace layout (bytes) ----  total 76,873,728 B = 73.3 MB
static const size_t OFF_QBF  = 0;          // [B][T][64] bf16   4 MB
static const size_t OFF_KBF  = 4194304;    // [B][T][64] bf16   4 MB
static const size_t OFF_VT   = 8388608;    // [B][C][T]  bf16  16 MB (v transposed)
static const size_t OFF_OA   = 25165824;   // [B][T][C]  fp32  32 MB (out_attn; later c2; first 16MB also xt)
static const size_t OFF_C1   = 58720256;   // [B][T][C]  bf16  16 MB (conv1 out)
static const size_t OFF_CRZ  = 75497472;   // [B][T] fp32 col 1/Z          (131072 B)
static const size_t OFF_RS   = 75628544;   // [B][T] fp32 rowsum           (131072 B)
static const size_t OFF_WX   = 75759616;   // [B][T] fp32 weight_x         (131072 B)
static const size_t OFF_W1   = 75890688;   // [3][256][256] bf16 W1 [j][o][c]  (393216 B)
static const size_t OFF_W2   = 76283904;   // [3][256][256] bf16 W2            (393216 B)
static const size_t OFF_WQKV = 76677120;   // [384][256] bf16 (q|k|v) [n][c]   (196608 B)

// ---------------------------------------------------------------------------
// weight-norm: one block per (conv, out-channel). R3: 8-block prep_kernel was
// the TOP dispatch (~100 us, latency-bound serial loops) -> 512 blocks now.
__global__ __launch_bounds__(256)
void wn_kernel(const float* __restrict__ v1, const float* __restrict__ g1,
               const float* __restrict__ v2, const float* __restrict__ g2,
               short* __restrict__ w1bf, short* __restrict__ w2bf) {
    __shared__ float red[4];
    int which = blockIdx.x >> 8, o = blockIdx.x & 255;
    const float* v = which ? v2 : v1;
    const float* g = which ? g2 : g1;
    short* wt = which ? w2bf : w1bf;
    const float* row = v + (size_t)o * 768;
    int tid = threadIdx.x, lane = tid & 63, wv_ = tid >> 6;
    float r0 = row[tid], r1 = row[tid + 256], r2 = row[tid + 512];
    float s = r0 * r0 + r1 * r1 + r2 * r2;
    for (int d = 1; d < 64; d <<= 1) s += __shfl_xor(s, d, 64);
    if (lane == 0) red[wv_] = s;
    __syncthreads();
    float scale = g[o] * rsqrtf(red[0] + red[1] + red[2] + red[3]);
    for (int j = 0; j < 3; ++j)
        wt[((size_t)(j * 256 + o)) * 256 + tid] = f2bf(scale * row[tid * 3 + j]);
}

// pack wq|wk|wv -> bf16 [n][c] (n: q 0-63, k 64-127, v 128-383)
__global__ __launch_bounds__(256)
void pack_kernel(const float* __restrict__ wq, const float* __restrict__ wk,
                 const float* __restrict__ wv, short* __restrict__ wqkvbf) {
    int n = blockIdx.x * 4 + (threadIdx.x >> 6);
    int c0 = (threadIdx.x & 63) * 4;
    for (int p = 0; p < 4; ++p) {
        int c = c0 + p;
        float w;
        if (n < 64)       w = wq[c * 64 + n];
        else if (n < 128) w = wk[c * 64 + n - 64];
        else              w = wv[c * 256 + n - 128];
        wqkvbf[(size_t)n * 256 + c] = f2bf(w);
    }
}

// ---------------------------------------------------------------------------
// x [b][c][t] fp32 -> xt [b][t][c] bf16  (64x64 tiles)
__global__ void transpose_kernel(const float* __restrict__ x, short* __restrict__ xt) {
    __shared__ float Tt[64 * 68];
    int tid = threadIdx.x;
    int c0 = blockIdx.x * 64, t0 = blockIdx.y * 64, b = blockIdx.z;
    for (int it = 0; it < 4; ++it) {
        int idx = tid + 256 * it;
        int cr = idx >> 4, tc = idx & 15;
        f4 v = *reinterpret_cast<const f4*>(&x[((size_t)b * CC + c0 + cr) * TT + t0 + tc * 4]);
        *reinterpret_cast<f4*>(&Tt[cr * 68 + tc * 4]) = v;
    }
    __syncthreads();
    for (int it = 0; it < 2; ++it) {
        int idx = tid + 256 * it;
        int tl = idx >> 3, seg = idx & 7;
        s8 o;
        for (int p = 0; p < 8; ++p) o[p] = f2bf(Tt[(seg * 8 + p) * 68 + tl]);
        *reinterpret_cast<s8*>(&xt[((size_t)b * TT + t0 + tl) * CC + c0 + seg * 8]) = o;
    }
}

// ---------------------------------------------------------------------------
// QKV GEMM: xt[b][t][c] bf16 @ wqkv[n][c] -> q/k bf16 [t][64], v -> vt bf16 [c][t]
__global__ __launch_bounds__(256, 3)
void qkv_kernel(const short* __restrict__ xt, const short* __restrict__ wqkv,
                const float* __restrict__ bq, const float* __restrict__ bk,
                const float* __restrict__ bv,
                short* __restrict__ qbf, short* __restrict__ kbf, short* __restrict__ vt) {
    __shared__ short SL[128 * 72 + 64 * 72];   // A (128t x 64c) then B (64n x 64c)
    short* Asm = SL;
    short* Bsm = SL + 128 * 72;
    int tid = threadIdx.x, wv_ = tid >> 6, lane = tid & 63;
    int n15 = lane & 15, quad = lane >> 4;
    int b = blockIdx.x >> 3, t0 = (blockIdx.x & 7) * 128;
    int n0 = blockIdx.y * 64;

    f32x4 acc[2][4];
    for (int i = 0; i < 2; ++i) for (int j = 0; j < 4; ++j)
        for (int p = 0; p < 4; ++p) acc[i][j][p] = 0.f;

    for (int kc = 0; kc < 4; ++kc) {
        int c0 = kc * 64;
        __syncthreads();
        for (int it = 0; it < 4; ++it) {           // A: 128 rows x 8 segs
            int idx = tid + 256 * it;
            int row = idx >> 3, seg = idx & 7;
            *reinterpret_cast<s8*>(&Asm[row * 72 + seg * 8]) =
                *reinterpret_cast<const s8*>(&xt[((size_t)b * TT + t0 + row) * CC + c0 + seg * 8]);
        }
        for (int it = 0; it < 2; ++it) {           // B: 64 rows x 8 segs
            int idx = tid + 256 * it;
            int row = idx >> 3, seg = idx & 7;
            *reinterpret_cast<s8*>(&Bsm[row * 72 + seg * 8]) =
                *reinterpret_cast<const s8*>(&wqkv[(size_t)(n0 + row) * 256 + c0 + seg * 8]);
        }
        __syncthreads();
        for (int ks = 0; ks < 2; ++ks)
            for (int mt2 = 0; mt2 < 2; ++mt2) {
                s8 a = *reinterpret_cast<const s8*>(&Asm[(wv_ * 32 + mt2 * 16 + n15) * 72 + quad * 8 + ks * 32]);
                for (int nt = 0; nt < 4; ++nt) {
                    s8 bb = *reinterpret_cast<const s8*>(&Bsm[(nt * 16 + n15) * 72 + quad * 8 + ks * 32]);
                    acc[mt2][nt] = __builtin_amdgcn_mfma_f32_16x16x32_bf16(a, bb, acc[mt2][nt], 0, 0, 0);
                }
            }
    }
    if (n0 < 128) {
        short* outp = (n0 == 0) ? qbf : kbf;
        const float* bias = (n0 == 0) ? bq : bk;
        for (int mt2 = 0; mt2 < 2; ++mt2)
            for (int nt = 0; nt < 4; ++nt) {
                int n_ = nt * 16 + n15;
                float bvl = bias[n_];
                for (int reg = 0; reg < 4; ++reg) {
                    int t = t0 + wv_ * 32 + mt2 * 16 + quad * 4 + reg;
                    outp[((size_t)b * TT + t) * 64 + n_] = f2bf(acc[mt2][nt][reg] + bvl);
                }
            }
    } else {
        int cbase = n0 - 128;
        __syncthreads();                           // reuse A/B LDS as transpose buffers
        short* Tw = SL + wv_ * 3072;               // per-wave 64n x 48(pad: 32 used)
        for (int mt2 = 0; mt2 < 2; ++mt2)
            for (int nt = 0; nt < 4; ++nt) {
                int n_ = nt * 16 + n15;
                float bvl = bv[cbase + n_];
                for (int reg = 0; reg < 4; ++reg)
                    Tw[n_ * 48 + mt2 * 16 + quad * 4 + reg] = f2bf(acc[mt2][nt][reg] + bvl);
            }
        for (int p = 0; p < 4; ++p) {              // wave-local RAW: lgkmcnt-ordered
            int n_ = (lane >> 2) + 16 * p;
            int seg = lane & 3;
            s8 vv = *reinterpret_cast<const s8*>(&Tw[n_ * 48 + seg * 8]);
            *reinterpret_cast<s8*>(&vt[((size_t)b * CC + cbase + n_) * TT + t0 + wv_ * 32 + seg * 8]) = vv;
        }
    }
}

// ---------------------------------------------------------------------------
// Per-key-column sum of exp(s/8) over q>=k (softmax over QUERY axis; no max
// subtraction needed: |s/8| bounded ~5). Writes 1/Z.
__global__ __launch_bounds__(256, 3)
void colz_kernel(const short* __restrict__ qbf, const short* __restrict__ kbf,
                 float* __restrict__ colrz) {
    __shared__ short Qs[64 * 72], Ks[64 * 72];
    __shared__ float red[4 * 64];
    int tid = threadIdx.x, wv_ = tid >> 6, lane = tid & 63;
    int n15 = lane & 15, quad = lane >> 4;
    int b = blockIdx.x >> 4, kt = blockIdx.x & 15;
    {
        int row = tid >> 2;
        for (int it = 0; it < 2; ++it) {
            int seg = (tid & 3) + 4 * it;
            *reinterpret_cast<s8*>(&Ks[row * 72 + seg * 8]) =
                *reinterpret_cast<const s8*>(&kbf[((size_t)b * TT + kt * 64 + row) * 64 + seg * 8]);
        }
    }
    float z[4] = {0.f, 0.f, 0.f, 0.f};
    for (int qt = kt; qt < 16; ++qt) {
        __syncthreads();
        {
            int row = tid >> 2;
            for (int it = 0; it < 2; ++it) {
                int seg = (tid & 3) + 4 * it;
                *reinterpret_cast<s8*>(&Qs[row * 72 + seg * 8]) =
                    *reinterpret_cast<const s8*>(&qbf[((size_t)b * TT + qt * 64 + row) * 64 + seg * 8]);
            }
        }
        __syncthreads();
        for (int nt = 0; nt < 4; ++nt) {
            f32x4 s;
            for (int p = 0; p < 4; ++p) s[p] = 0.f;
            for (int ks = 0; ks < 2; ++ks) {
                s8 a  = *reinterpret_cast<const s8*>(&Qs[(wv_ * 16 + n15) * 72 + quad * 8 + ks * 32]);
                s8 bb = *reinterpret_cast<const s8*>(&Ks[(nt * 16 + n15) * 72 + quad * 8 + ks * 32]);
                s = __builtin_amdgcn_mfma_f32_16x16x32_bf16(a, bb, s, 0, 0, 0);
            }
            int kg = kt * 64 + nt * 16 + n15;
            int qbase = qt * 64 + wv_ * 16 + quad * 4;
            if (qt > kt) {
                for (int reg = 0; reg < 4; ++reg) z[nt] += __expf(s[reg] * 0.125f);
            } else {
                for (int reg = 0; reg < 4; ++reg)
                    if (qbase + reg >= kg) z[nt] += __expf(s[reg] * 0.125f);
            }
        }
    }
    for (int nt = 0; nt < 4; ++nt) {
        z[nt] += __shfl_xor(z[nt], 16, 64);
        z[nt] += __shfl_xor(z[nt], 32, 64);
    }
    if (lane < 16)
        for (int nt = 0; nt < 4; ++nt) red[wv_ * 64 + nt * 16 + lane] = z[nt];
    __syncthreads();
    if (tid < 64) {
        float Z = red[tid] + red[64 + tid] + red[128 + tid] + red[192 + tid];
        colrz[(size_t)b * TT + kt * 64 + tid] = 1.0f / Z;
    }
}

// ---------------------------------------------------------------------------
// Attention apply: p = exp(s/8)*rz[k] (q>=k), out_attn += P @ V (MFMA),
// rowsum = sum_k p. Grid (b*16+qt', ch); big qt first for balance.
__global__ __launch_bounds__(256, 3)
void attn_kernel(const short* __restrict__ qbf, const short* __restrict__ kbf,
                 const short* __restrict__ vt, const float* __restrict__ colrz,
                 float* __restrict__ oa, float* __restrict__ rowsum) {
    __shared__ short Qs[64 * 72];
    __shared__ short Ks[64 * 72];
    __shared__ short Ps[64 * 72];   // [q][k] bf16 = PV A-operand
    __shared__ short Vs[128 * 72];  // [c][t_k] bf16 = PV B-operand
    __shared__ float redR[64];
    int tid = threadIdx.x, wv_ = tid >> 6, lane = tid & 63;
    int n15 = lane & 15, quad = lane >> 4;
    int b = blockIdx.x >> 4, qt = 15 - (blockIdx.x & 15);   // big tiles first
    int ch = blockIdx.y;
    {
        int row = tid >> 2;
        for (int it = 0; it < 2; ++it) {
            int seg = (tid & 3) + 4 * it;
            *reinterpret_cast<s8*>(&Qs[row * 72 + seg * 8]) =
                *reinterpret_cast<const s8*>(&qbf[((size_t)b * TT + qt * 64 + row) * 64 + seg * 8]);
        }
    }
    f32x4 acc[8];
    for (int i = 0; i < 8; ++i) for (int p = 0; p < 4; ++p) acc[i][p] = 0.f;
    float rsum[4] = {0.f, 0.f, 0.f, 0.f};

    for (int kt = 0; kt <= qt; ++kt) {
        __syncthreads();
        {
            int row = tid >> 2;
            for (int it = 0; it < 2; ++it) {
                int seg = (tid & 3) + 4 * it;
                *reinterpret_cast<s8*>(&Ks[row * 72 + seg * 8]) =
                    *reinterpret_cast<const s8*>(&kbf[((size_t)b * TT + kt * 64 + row) * 64 + seg * 8]);
            }
        }
        for (int it = 0; it < 4; ++it) {
            int idx = tid + 256 * it;
            int row = idx >> 3, seg = idx & 7;
            *reinterpret_cast<s8*>(&Vs[row * 72 + seg * 8]) =
                *reinterpret_cast<const s8*>(&vt[((size_t)b * CC + ch * 128 + row) * TT + kt * 64 + seg * 8]);
        }
        __syncthreads();
        // scores -> p -> Ps (each wave touches only its own 16 q rows of Ps)
        for (int nt = 0; nt < 4; ++nt) {
            f32x4 s;
            for (int p = 0; p < 4; ++p) s[p] = 0.f;
            for (int ks = 0; ks < 2; ++ks) {
                s8 a  = *reinterpret_cast<const s8*>(&Qs[(wv_ * 16 + n15) * 72 + quad * 8 + ks * 32]);
                s8 bb = *reinterpret_cast<const s8*>(&Ks[(nt * 16 + n15) * 72 + quad * 8 + ks * 32]);
                s = __builtin_amdgcn_mfma_f32_16x16x32_bf16(a, bb, s, 0, 0, 0);
            }
            int kg = kt * 64 + nt * 16 + n15;
            float rz = colrz[(size_t)b * TT + kg];
            int qbase = qt * 64 + wv_ * 16 + quad * 4;
            for (int reg = 0; reg < 4; ++reg) {
                float p = 0.f;
                if (kt < qt || qbase + reg >= kg) p = __expf(s[reg] * 0.125f) * rz;
                rsum[reg] += p;
                Ps[(wv_ * 16 + quad * 4 + reg) * 72 + nt * 16 + n15] = f2bf(p);
            }
        }
        // PV: Ps rows are wave-private (lgkmcnt-ordered), Vs covered by barrier
        for (int ks = 0; ks < 2; ++ks) {
            s8 a = *reinterpret_cast<const s8*>(&Ps[(wv_ * 16 + n15) * 72 + quad * 8 + ks * 32]);
            for (int nt = 0; nt < 8; ++nt) {
                s8 bb = *reinterpret_cast<const s8*>(&Vs[(nt * 16 + n15) * 72 + quad * 8 + ks * 32]);
                acc[nt] = __builtin_amdgcn_mfma_f32_16x16x32_bf16(a, bb, acc[nt], 0, 0, 0);
            }
        }
    }
    if (ch == 0) {
        for (int reg = 0; reg < 4; ++reg) {
            float v = rsum[reg];
            v += __shfl_xor(v, 1, 64);
            v += __shfl_xor(v, 2, 64);
            v += __shfl_xor(v, 4, 64);
            v += __shfl_xor(v, 8, 64);
            if (n15 == 0) redR[wv_ * 16 + quad * 4 + reg] = v;
        }
    }
    for (int nt = 0; nt < 8; ++nt) {
        int c = ch * 128 + nt * 16 + n15;
        for (int reg = 0; reg < 4; ++reg) {
            int q = qt * 64 + wv_ * 16 + quad * 4 + reg;
            oa[((size_t)b * TT + q) * CC + c] = acc[nt][reg];
        }
    }
    if (ch == 0) {
        __syncthreads();
        if (tid < 64) rowsum[(size_t)b * TT + qt * 64 + tid] = redR[tid];
    }
}

// ---------------------------------------------------------------------------
// Causal K=3 conv as MFMA GEMM: out[t,o] = relu(b[o] + sum_{j,c} in[t-2+j,c]*W[j][o][c])
// A tile: 130-row halo [t][c]; B: [j][o][c]. Block 128t x 64o.
__global__ __launch_bounds__(256, 3)
void conv_kernel(const void* __restrict__ inp, int in_is_fp32,
                 const short* __restrict__ wbf, const float* __restrict__ bias,
                 void* __restrict__ outp, int out_is_bf16) {
    __shared__ short As[130 * 72];
    __shared__ short Bs[3 * 64 * 72];
    int tid = threadIdx.x, wv_ = tid >> 6, lane = tid & 63;
    int n15 = lane & 15, quad = lane >> 4;
    int b = blockIdx.x >> 3, mt = blockIdx.x & 7;
    int n0 = blockIdx.y * 64;
    int t0 = mt * 128;
    f32x4 acc[2][4];
    for (int i = 0; i < 2; ++i) for (int j = 0; j < 4; ++j)
        for (int p = 0; p < 4; ++p) acc[i][j][p] = 0.f;

    for (int kc = 0; kc < 4; ++kc) {
        int c0 = kc * 64;
        __syncthreads();
        if (in_is_fp32) {
            const float* in = (const float*)inp;
            for (int it = 0; it < 9; ++it) {
                int idx = tid + 256 * it;
                int row = idx >> 4, fc = idx & 15;
                if (row < 130) {
                    int t = t0 + row - 2;
                    s4v st;
                    if (t >= 0) {
                        f4 v = *reinterpret_cast<const f4*>(&in[((size_t)b * TT + t) * CC + c0 + fc * 4]);
                        for (int p = 0; p < 4; ++p) st[p] = f2bf(v[p]);
                    } else { for (int p = 0; p < 4; ++p) st[p] = 0; }
                    *reinterpret_cast<s4v*>(&As[row * 72 + fc * 4]) = st;
                }
            }
        } else {
            const short* in = (const short*)inp;
            for (int it = 0; it < 5; ++it) {
                int idx = tid + 256 * it;
                int row = idx >> 3, seg = idx & 7;
                if (row < 130) {
                    int t = t0 + row - 2;
                    s8 st;
                    if (t >= 0) st = *reinterpret_cast<const s8*>(&in[((size_t)b * TT + t) * CC + c0 + seg * 8]);
                    else for (int p = 0; p < 8; ++p) st[p] = 0;
                    *reinterpret_cast<s8*>(&As[row * 72 + seg * 8]) = st;
                }
            }
        }
        for (int it = 0; it < 6; ++it) {     // B: 192 rows (j,o) x 8 segs
            int idx = tid + 256 * it;
            int row = idx >> 3, seg = idx & 7;
            int j = row >> 6, o = row & 63;
            *reinterpret_cast<s8*>(&Bs[row * 72 + seg * 8]) =
                *reinterpret_cast<const s8*>(&wbf[((size_t)(j * 256 + n0 + o)) * 256 + c0 + seg * 8]);
        }
        __syncthreads();
        for (int j = 0; j < 3; ++j)
            for (int ks = 0; ks < 2; ++ks)
                for (int mt2 = 0; mt2 < 2; ++mt2) {
                    s8 a = *reinterpret_cast<const s8*>(&As[(wv_ * 32 + mt2 * 16 + n15 + j) * 72 + quad * 8 + ks * 32]);
                    for (int nt = 0; nt < 4; ++nt) {
                        s8 bb = *reinterpret_cast<const s8*>(&Bs[(j * 64 + nt * 16 + n15) * 72 + quad * 8 + ks * 32]);
                        acc[mt2][nt] = __builtin_amdgcn_mfma_f32_16x16x32_bf16(a, bb, acc[mt2][nt], 0, 0, 0);
                    }
                }
    }
    for (int mt2 = 0; mt2 < 2; ++mt2)
        for (int nt = 0; nt < 4; ++nt) {
            int o = n0 + nt * 16 + n15;
            float bvl = bias[o];
            for (int reg = 0; reg < 4; ++reg) {
                int t = t0 + wv_ * 32 + mt2 * 16 + quad * 4 + reg;
                float v = fmaxf(acc[mt2][nt][reg] + bvl, 0.f);
                if (out_is_bf16) ((short*)outp)[((size_t)b * TT + t) * CC + o] = f2bf(v);
                else             ((float*)outp)[((size_t)b * TT + t) * CC + o] = v;
            }
        }
}

// ---------------------------------------------------------------------------
__global__ void rowsm_kernel(const float* __restrict__ rowsum, float* __restrict__ wx) {
    __shared__ float red[256];
    int b = blockIdx.x, tid = threadIdx.x;
    float v[4];
    float m = -1e30f;
    for (int r = 0; r < 4; ++r) { v[r] = rowsum[(size_t)b * TT + tid + 256 * r]; m = fmaxf(m, v[r]); }
    red[tid] = m; __syncthreads();
    for (int s = 128; s > 0; s >>= 1) { if (tid < s) red[tid] = fmaxf(red[tid], red[tid + s]); __syncthreads(); }
    m = red[0]; __syncthreads();
    float e[4], zs = 0.f;
    for (int r = 0; r < 4; ++r) { e[r] = __expf(v[r] - m); zs += e[r]; }
    red[tid] = zs; __syncthreads();
    for (int s = 128; s > 0; s >>= 1) { if (tid < s) red[tid] += red[tid + s]; __syncthreads(); }
    float rz = 1.0f / red[0];
    for (int r = 0; r < 4; ++r) wx[(size_t)b * TT + tid + 256 * r] = e[r] * rz;
}

// ---------------------------------------------------------------------------
__global__ void final_kernel(const float* __restrict__ c2, const float* __restrict__ x,
                             const float* __restrict__ wx, float* __restrict__ out) {
    __shared__ float tile[32 * 33];
    int tid = threadIdx.x;
    int c0 = blockIdx.x * 32, t0 = blockIdx.y * 32, b = blockIdx.z;
    int tl = tid >> 3, c4 = (tid & 7) * 4;
    f4 v = *reinterpret_cast<const f4*>(&c2[((size_t)b * TT + t0 + tl) * CC + c0 + c4]);
    for (int p = 0; p < 4; ++p) tile[tl * 33 + c4 + p] = v[p];
    __syncthreads();
    int cl = tid >> 3, t4 = (tid & 7) * 4;
    f4 x4 = *reinterpret_cast<const f4*>(&x[((size_t)b * CC + c0 + cl) * TT + t0 + t4]);
    f4 w4 = *reinterpret_cast<const f4*>(&wx[(size_t)b * TT + t0 + t4]);
    f4 r;
    for (int p = 0; p < 4; ++p) {
        float cv = tile[(t4 + p) * 33 + cl];
        r[p] = fmaxf(cv + x4[p] * (1.f + w4[p]), 0.f);
    }
    *reinterpret_cast<f4*>(&out[((size_t)b * CC + c0 + cl) * TT + t0 + t4]) = r;
}

// ---------------------------------------------------------------------------
extern "C" void kernel_launch(void* const* d_in, const int* in_sizes, int n_in,
                              void* d_out, int out_size, void* d_ws, size_t ws_size,
                              hipStream_t stream) {
    (void)in_sizes; (void)n_in; (void)out_size; (void)ws_size;
    const float* x  = (const float*)d_in[0];
    const float* wq = (const float*)d_in[1];
    const float* bq = (const float*)d_in[2];
    const float* wk = (const float*)d_in[3];
    const float* bk = (const float*)d_in[4];
    const float* wv = (const float*)d_in[5];
    const float* bv = (const float*)d_in[6];
    const float* v1 = (const float*)d_in[7];
    const float* g1 = (const float*)d_in[8];
    const float* b1 = (const float*)d_in[9];
    const float* v2 = (const float*)d_in[10];
    const float* g2 = (const float*)d_in[11];
    const float* b2 = (const float*)d_in[12];
    char* ws = (char*)d_ws;
    float* out = (float*)d_out;

    short* qbf  = (short*)(ws + OFF_QBF);
    short* kbf  = (short*)(ws + OFF_KBF);
    short* vt   = (short*)(ws + OFF_VT);
    float* oa   = (float*)(ws + OFF_OA);     // out_attn fp32; later c2
    short* xt   = (short*)(ws + OFF_OA);     // xt bf16 (dead before oa written)
    short* c1   = (short*)(ws + OFF_C1);
    float* crz  = (float*)(ws + OFF_CRZ);
    float* rs   = (float*)(ws + OFF_RS);
    float* wxb  = (float*)(ws + OFF_WX);
    short* w1bf = (short*)(ws + OFF_W1);
    short* w2bf = (short*)(ws + OFF_W2);
    short* wqkv = (short*)(ws + OFF_WQKV);

    wn_kernel<<<dim3(512), dim3(256), 0, stream>>>(v1, g1, v2, g2, w1bf, w2bf);
    pack_kernel<<<dim3(96), dim3(256), 0, stream>>>(wq, wk, wv, wqkv);
    transpose_kernel<<<dim3(4, 16, 32), dim3(256), 0, stream>>>(x, xt);
    qkv_kernel<<<dim3(256, 6), dim3(256), 0, stream>>>(xt, wqkv, bq, bk, bv, qbf, kbf, vt);
    colz_kernel<<<dim3(512), dim3(256), 0, stream>>>(qbf, kbf, crz);
    attn_kernel<<<dim3(512, 2), dim3(256), 0, stream>>>(qbf, kbf, vt, crz, oa, rs);
    conv_kernel<<<dim3(256, 4), dim3(256), 0, stream>>>(oa, 1, w1bf, b1, c1, 1);
    conv_kernel<<<dim3(256, 4), dim3(256), 0, stream>>>(c1, 0, w2bf, b2, oa, 0);
    rowsm_kernel<<<dim3(32), dim3(256), 0, stream>>>(rs, wxb);
    final_kernel<<<dim3(8, 32, 32), dim3(256), 0, stream>>>(oa, x, wxb, out);
}

// Round 5
// 266.674 us; speedup vs baseline: 4.2887x; 1.0502x over previous
//
#include <hip/hip_runtime.h>
#include <math.h>

#define BB 32
#define CC 256
#define TT 1024

typedef __attribute__((ext_vector_type(4))) float f4;
typedef __attribute__((ext_vector_type(4))) float f32x4;
typedef __attribute__((ext_vector_type(8))) short s8;   // bf16x8 MFMA frag (4 VGPRs)
typedef __attribute__((ext_vector_type(4))) short s4v;  // 8B LDS store

__device__ inline short f2bf(float f) {                 // RNE fp32->bf16
    unsigned u = __builtin_bit_cast(unsigned, f);
    u = (u + 0x7FFFu + ((u >> 16) & 1u)) >> 16;
    return (short)u;
}

// ---- workspace layout (bytes) ----  total 76,873,728 B = 73.3 MB
static const size_t OFF_QBF  = 0;          // [B][T][64] bf16   4 MB
static const size_t OFF_KBF  = 4194304;    // [B][T][64] bf16   4 MB
static const size_t OFF_VT   = 8388608;    // [B][C][T]  bf16  16 MB (v transposed)
static const size_t OFF_OA   = 25165824;   // [B][T][C]  fp32  32 MB (out_attn; later c2; first 16MB also xt)
static const size_t OFF_C1   = 58720256;   // [B][T][C]  bf16  16 MB (conv1 out)
static const size_t OFF_CRZ  = 75497472;   // [B][T] fp32 col 1/Z          (131072 B)
static const size_t OFF_RS   = 75628544;   // [B][T] fp32 rowsum           (131072 B)
static const size_t OFF_WX   = 75759616;   // [B][T] fp32 weight_x         (131072 B)
static const size_t OFF_W1   = 75890688;   // [3][256][256] bf16 W1 [j][o][c]  (393216 B)
static const size_t OFF_W2   = 76283904;   // [3][256][256] bf16 W2            (393216 B)
static const size_t OFF_WQKV = 76677120;   // [384][256] bf16 (q|k|v) [n][c]   (196608 B)

// ---------------------------------------------------------------------------
// weight-norm: one block per (conv, out-channel)
__global__ __launch_bounds__(256)
void wn_kernel(const float* __restrict__ v1, const float* __restrict__ g1,
               const float* __restrict__ v2, const float* __restrict__ g2,
               short* __restrict__ w1bf, short* __restrict__ w2bf) {
    __shared__ float red[4];
    int which = blockIdx.x >> 8, o = blockIdx.x & 255;
    const float* v = which ? v2 : v1;
    const float* g = which ? g2 : g1;
    short* wt = which ? w2bf : w1bf;
    const float* row = v + (size_t)o * 768;
    int tid = threadIdx.x, lane = tid & 63, wv_ = tid >> 6;
    float r0 = row[tid], r1 = row[tid + 256], r2 = row[tid + 512];
    float s = r0 * r0 + r1 * r1 + r2 * r2;
    for (int d = 1; d < 64; d <<= 1) s += __shfl_xor(s, d, 64);
    if (lane == 0) red[wv_] = s;
    __syncthreads();
    float scale = g[o] * rsqrtf(red[0] + red[1] + red[2] + red[3]);
    for (int j = 0; j < 3; ++j)
        wt[((size_t)(j * 256 + o)) * 256 + tid] = f2bf(scale * row[tid * 3 + j]);
}

// pack wq|wk|wv -> bf16 [n][c] (n: q 0-63, k 64-127, v 128-383)
__global__ __launch_bounds__(256)
void pack_kernel(const float* __restrict__ wq, const float* __restrict__ wk,
                 const float* __restrict__ wv, short* __restrict__ wqkvbf) {
    int n = blockIdx.x * 4 + (threadIdx.x >> 6);
    int c0 = (threadIdx.x & 63) * 4;
    for (int p = 0; p < 4; ++p) {
        int c = c0 + p;
        float w;
        if (n < 64)       w = wq[c * 64 + n];
        else if (n < 128) w = wk[c * 64 + n - 64];
        else              w = wv[c * 256 + n - 128];
        wqkvbf[(size_t)n * 256 + c] = f2bf(w);
    }
}

// ---------------------------------------------------------------------------
// x [b][c][t] fp32 -> xt [b][t][c] bf16  (64x64 tiles)
__global__ void transpose_kernel(const float* __restrict__ x, short* __restrict__ xt) {
    __shared__ float Tt[64 * 68];
    int tid = threadIdx.x;
    int c0 = blockIdx.x * 64, t0 = blockIdx.y * 64, b = blockIdx.z;
    for (int it = 0; it < 4; ++it) {
        int idx = tid + 256 * it;
        int cr = idx >> 4, tc = idx & 15;
        f4 v = *reinterpret_cast<const f4*>(&x[((size_t)b * CC + c0 + cr) * TT + t0 + tc * 4]);
        *reinterpret_cast<f4*>(&Tt[cr * 68 + tc * 4]) = v;
    }
    __syncthreads();
    for (int it = 0; it < 2; ++it) {
        int idx = tid + 256 * it;
        int tl = idx >> 3, seg = idx & 7;
        s8 o;
        for (int p = 0; p < 8; ++p) o[p] = f2bf(Tt[(seg * 8 + p) * 68 + tl]);
        *reinterpret_cast<s8*>(&xt[((size_t)b * TT + t0 + tl) * CC + c0 + seg * 8]) = o;
    }
}

// ---------------------------------------------------------------------------
// QKV GEMM: xt[b][t][c] bf16 @ wqkv[n][c] -> q/k bf16 [t][64], v -> vt bf16 [c][t]
__global__ __launch_bounds__(256, 3)
void qkv_kernel(const short* __restrict__ xt, const short* __restrict__ wqkv,
                const float* __restrict__ bq, const float* __restrict__ bk,
                const float* __restrict__ bv,
                short* __restrict__ qbf, short* __restrict__ kbf, short* __restrict__ vt) {
    __shared__ short SL[128 * 72 + 64 * 72];   // A (128t x 64c) then B (64n x 64c)
    short* Asm = SL;
    short* Bsm = SL + 128 * 72;
    int tid = threadIdx.x, wv_ = tid >> 6, lane = tid & 63;
    int n15 = lane & 15, quad = lane >> 4;
    int b = blockIdx.x >> 3, t0 = (blockIdx.x & 7) * 128;
    int n0 = blockIdx.y * 64;

    f32x4 acc[2][4];
    for (int i = 0; i < 2; ++i) for (int j = 0; j < 4; ++j)
        for (int p = 0; p < 4; ++p) acc[i][j][p] = 0.f;

    for (int kc = 0; kc < 4; ++kc) {
        int c0 = kc * 64;
        __syncthreads();
        for (int it = 0; it < 4; ++it) {           // A: 128 rows x 8 segs
            int idx = tid + 256 * it;
            int row = idx >> 3, seg = idx & 7;
            *reinterpret_cast<s8*>(&Asm[row * 72 + seg * 8]) =
                *reinterpret_cast<const s8*>(&xt[((size_t)b * TT + t0 + row) * CC + c0 + seg * 8]);
        }
        for (int it = 0; it < 2; ++it) {           // B: 64 rows x 8 segs
            int idx = tid + 256 * it;
            int row = idx >> 3, seg = idx & 7;
            *reinterpret_cast<s8*>(&Bsm[row * 72 + seg * 8]) =
                *reinterpret_cast<const s8*>(&wqkv[(size_t)(n0 + row) * 256 + c0 + seg * 8]);
        }
        __syncthreads();
        for (int ks = 0; ks < 2; ++ks)
            for (int mt2 = 0; mt2 < 2; ++mt2) {
                s8 a = *reinterpret_cast<const s8*>(&Asm[(wv_ * 32 + mt2 * 16 + n15) * 72 + quad * 8 + ks * 32]);
                for (int nt = 0; nt < 4; ++nt) {
                    s8 bb = *reinterpret_cast<const s8*>(&Bsm[(nt * 16 + n15) * 72 + quad * 8 + ks * 32]);
                    acc[mt2][nt] = __builtin_amdgcn_mfma_f32_16x16x32_bf16(a, bb, acc[mt2][nt], 0, 0, 0);
                }
            }
    }
    if (n0 < 128) {
        short* outp = (n0 == 0) ? qbf : kbf;
        const float* bias = (n0 == 0) ? bq : bk;
        for (int mt2 = 0; mt2 < 2; ++mt2)
            for (int nt = 0; nt < 4; ++nt) {
                int n_ = nt * 16 + n15;
                float bvl = bias[n_];
                for (int reg = 0; reg < 4; ++reg) {
                    int t = t0 + wv_ * 32 + mt2 * 16 + quad * 4 + reg;
                    outp[((size_t)b * TT + t) * 64 + n_] = f2bf(acc[mt2][nt][reg] + bvl);
                }
            }
    } else {
        int cbase = n0 - 128;
        __syncthreads();                           // reuse A/B LDS as transpose buffers
        short* Tw = SL + wv_ * 3072;               // per-wave 64n x 48(pad: 32 used)
        for (int mt2 = 0; mt2 < 2; ++mt2)
            for (int nt = 0; nt < 4; ++nt) {
                int n_ = nt * 16 + n15;
                float bvl = bv[cbase + n_];
                for (int reg = 0; reg < 4; ++reg)
                    Tw[n_ * 48 + mt2 * 16 + quad * 4 + reg] = f2bf(acc[mt2][nt][reg] + bvl);
            }
        for (int p = 0; p < 4; ++p) {              // wave-local RAW: lgkmcnt-ordered
            int n_ = (lane >> 2) + 16 * p;
            int seg = lane & 3;
            s8 vv = *reinterpret_cast<const s8*>(&Tw[n_ * 48 + seg * 8]);
            *reinterpret_cast<s8*>(&vt[((size_t)b * CC + cbase + n_) * TT + t0 + wv_ * 32 + seg * 8]) = vv;
        }
    }
}

// ---------------------------------------------------------------------------
// Per-key-column sum of exp(s/8) over q>=k. R4: latency-bound -> prefetch next
// Q tile into regs so the global load overlaps the MFMA+exp compute.
__global__ __launch_bounds__(256, 3)
void colz_kernel(const short* __restrict__ qbf, const short* __restrict__ kbf,
                 float* __restrict__ colrz) {
    __shared__ short Qs[64 * 72], Ks[64 * 72];
    __shared__ float red[4 * 64];
    int tid = threadIdx.x, wv_ = tid >> 6, lane = tid & 63;
    int n15 = lane & 15, quad = lane >> 4;
    int b = blockIdx.x >> 4, kt = blockIdx.x & 15;
    int row = tid >> 2, sg0 = (tid & 3) * 8;
    {
        const short* kp = &kbf[((size_t)b * TT + kt * 64 + row) * 64];
        *reinterpret_cast<s8*>(&Ks[row * 72 + sg0]) = *reinterpret_cast<const s8*>(&kp[sg0]);
        *reinterpret_cast<s8*>(&Ks[row * 72 + sg0 + 32]) = *reinterpret_cast<const s8*>(&kp[sg0 + 32]);
    }
    s8 qreg0, qreg1;
    {
        const short* qp = &qbf[((size_t)b * TT + kt * 64 + row) * 64];
        qreg0 = *reinterpret_cast<const s8*>(&qp[sg0]);
        qreg1 = *reinterpret_cast<const s8*>(&qp[sg0 + 32]);
    }
    float z[4] = {0.f, 0.f, 0.f, 0.f};
    for (int qt = kt; qt < 16; ++qt) {
        __syncthreads();
        *reinterpret_cast<s8*>(&Qs[row * 72 + sg0]) = qreg0;
        *reinterpret_cast<s8*>(&Qs[row * 72 + sg0 + 32]) = qreg1;
        __syncthreads();
        if (qt < 15) {
            const short* qp = &qbf[((size_t)b * TT + (qt + 1) * 64 + row) * 64];
            qreg0 = *reinterpret_cast<const s8*>(&qp[sg0]);
            qreg1 = *reinterpret_cast<const s8*>(&qp[sg0 + 32]);
        }
        for (int nt = 0; nt < 4; ++nt) {
            f32x4 s;
            for (int p = 0; p < 4; ++p) s[p] = 0.f;
            for (int ks = 0; ks < 2; ++ks) {
                s8 a  = *reinterpret_cast<const s8*>(&Qs[(wv_ * 16 + n15) * 72 + quad * 8 + ks * 32]);
                s8 bb = *reinterpret_cast<const s8*>(&Ks[(nt * 16 + n15) * 72 + quad * 8 + ks * 32]);
                s = __builtin_amdgcn_mfma_f32_16x16x32_bf16(a, bb, s, 0, 0, 0);
            }
            int kg = kt * 64 + nt * 16 + n15;
            int qbase = qt * 64 + wv_ * 16 + quad * 4;
            if (qt > kt) {
                for (int reg = 0; reg < 4; ++reg) z[nt] += __expf(s[reg] * 0.125f);
            } else {
                for (int reg = 0; reg < 4; ++reg)
                    if (qbase + reg >= kg) z[nt] += __expf(s[reg] * 0.125f);
            }
        }
    }
    for (int nt = 0; nt < 4; ++nt) {
        z[nt] += __shfl_xor(z[nt], 16, 64);
        z[nt] += __shfl_xor(z[nt], 32, 64);
    }
    if (lane < 16)
        for (int nt = 0; nt < 4; ++nt) red[wv_ * 64 + nt * 16 + lane] = z[nt];
    __syncthreads();
    if (tid < 64) {
        float Z = red[tid] + red[64 + tid] + red[128 + tid] + red[192 + tid];
        colrz[(size_t)b * TT + kt * 64 + tid] = 1.0f / Z;
    }
}

// ---------------------------------------------------------------------------
// Attention apply, R5 restructure:
//  - one block per (b, qt): all 256 V cols staged (no ch split) -> QK MFMA and
//    exp/Ps VALU computed ONCE instead of twice
//  - K/V tile kt+1 prefetched into regs so global latency overlaps compute
__global__ __launch_bounds__(256, 2)
void attn_kernel(const short* __restrict__ qbf, const short* __restrict__ kbf,
                 const short* __restrict__ vt, const float* __restrict__ colrz,
                 float* __restrict__ oa, float* __restrict__ rowsum) {
    __shared__ short Qs[64 * 72];
    __shared__ short Ks[64 * 72];
    __shared__ short Ps[64 * 72];   // [q][k] bf16 = PV A-operand
    __shared__ short Vs[256 * 72];  // [c][t_k] bf16 = PV B-operand (all 256 c)
    __shared__ float redR[64];
    int tid = threadIdx.x, wv_ = tid >> 6, lane = tid & 63;
    int n15 = lane & 15, quad = lane >> 4;
    int b = blockIdx.x >> 4, qt = 15 - (blockIdx.x & 15);   // big tiles first
    int row = tid >> 2, sg0 = (tid & 3) * 8;
    {
        const short* qp = &qbf[((size_t)b * TT + qt * 64 + row) * 64];
        *reinterpret_cast<s8*>(&Qs[row * 72 + sg0]) = *reinterpret_cast<const s8*>(&qp[sg0]);
        *reinterpret_cast<s8*>(&Qs[row * 72 + sg0 + 32]) = *reinterpret_cast<const s8*>(&qp[sg0 + 32]);
    }
    f32x4 acc[16];
    for (int i = 0; i < 16; ++i) for (int p = 0; p < 4; ++p) acc[i][p] = 0.f;
    float rsum[4] = {0.f, 0.f, 0.f, 0.f};

    s8 kreg0, kreg1, vreg[8];
    {   // load tile kt=0
        const short* kp = &kbf[((size_t)b * TT + 0 * 64 + row) * 64];
        kreg0 = *reinterpret_cast<const s8*>(&kp[sg0]);
        kreg1 = *reinterpret_cast<const s8*>(&kp[sg0 + 32]);
        for (int it = 0; it < 8; ++it) {
            int idx = tid + 256 * it;
            int vr = idx >> 3, seg = idx & 7;
            vreg[it] = *reinterpret_cast<const s8*>(&vt[((size_t)b * CC + vr) * TT + 0 + seg * 8]);
        }
    }

    for (int kt = 0; kt <= qt; ++kt) {
        __syncthreads();
        *reinterpret_cast<s8*>(&Ks[row * 72 + sg0]) = kreg0;
        *reinterpret_cast<s8*>(&Ks[row * 72 + sg0 + 32]) = kreg1;
        for (int it = 0; it < 8; ++it) {
            int idx = tid + 256 * it;
            int vr = idx >> 3, seg = idx & 7;
            *reinterpret_cast<s8*>(&Vs[vr * 72 + seg * 8]) = vreg[it];
        }
        __syncthreads();
        if (kt < qt) {   // prefetch kt+1 (overlaps the compute below)
            const short* kp = &kbf[((size_t)b * TT + (kt + 1) * 64 + row) * 64];
            kreg0 = *reinterpret_cast<const s8*>(&kp[sg0]);
            kreg1 = *reinterpret_cast<const s8*>(&kp[sg0 + 32]);
            for (int it = 0; it < 8; ++it) {
                int idx = tid + 256 * it;
                int vr = idx >> 3, seg = idx & 7;
                vreg[it] = *reinterpret_cast<const s8*>(&vt[((size_t)b * CC + vr) * TT + (kt + 1) * 64 + seg * 8]);
            }
        }
        // scores -> p -> Ps (each wave touches only its own 16 q rows of Ps)
        for (int nt = 0; nt < 4; ++nt) {
            f32x4 s;
            for (int p = 0; p < 4; ++p) s[p] = 0.f;
            for (int ks = 0; ks < 2; ++ks) {
                s8 a  = *reinterpret_cast<const s8*>(&Qs[(wv_ * 16 + n15) * 72 + quad * 8 + ks * 32]);
                s8 bb = *reinterpret_cast<const s8*>(&Ks[(nt * 16 + n15) * 72 + quad * 8 + ks * 32]);
                s = __builtin_amdgcn_mfma_f32_16x16x32_bf16(a, bb, s, 0, 0, 0);
            }
            int kg = kt * 64 + nt * 16 + n15;
            float rz = colrz[(size_t)b * TT + kg];
            int qbase = qt * 64 + wv_ * 16 + quad * 4;
            for (int reg = 0; reg < 4; ++reg) {
                float p = 0.f;
                if (kt < qt || qbase + reg >= kg) p = __expf(s[reg] * 0.125f) * rz;
                rsum[reg] += p;
                Ps[(wv_ * 16 + quad * 4 + reg) * 72 + nt * 16 + n15] = f2bf(p);
            }
        }
        // PV over all 16 c-tiles; Ps rows wave-private (lgkmcnt-ordered)
        for (int ks = 0; ks < 2; ++ks) {
            s8 a = *reinterpret_cast<const s8*>(&Ps[(wv_ * 16 + n15) * 72 + quad * 8 + ks * 32]);
            for (int nt = 0; nt < 16; ++nt) {
                s8 bb = *reinterpret_cast<const s8*>(&Vs[(nt * 16 + n15) * 72 + quad * 8 + ks * 32]);
                acc[nt] = __builtin_amdgcn_mfma_f32_16x16x32_bf16(a, bb, acc[nt], 0, 0, 0);
            }
        }
    }
    for (int reg = 0; reg < 4; ++reg) {
        float v = rsum[reg];
        v += __shfl_xor(v, 1, 64);
        v += __shfl_xor(v, 2, 64);
        v += __shfl_xor(v, 4, 64);
        v += __shfl_xor(v, 8, 64);
        if (n15 == 0) redR[wv_ * 16 + quad * 4 + reg] = v;
    }
    for (int nt = 0; nt < 16; ++nt) {
        int c = nt * 16 + n15;
        for (int reg = 0; reg < 4; ++reg) {
            int q = qt * 64 + wv_ * 16 + quad * 4 + reg;
            oa[((size_t)b * TT + q) * CC + c] = acc[nt][reg];
        }
    }
    __syncthreads();
    if (tid < 64) rowsum[(size_t)b * TT + qt * 64 + tid] = redR[tid];
}

// ---------------------------------------------------------------------------
// Causal K=3 conv as MFMA GEMM: out[t,o] = relu(b[o] + sum_{j,c} in[t-2+j,c]*W[j][o][c])
__global__ __launch_bounds__(256, 3)
void conv_kernel(const void* __restrict__ inp, int in_is_fp32,
                 const short* __restrict__ wbf, const float* __restrict__ bias,
                 void* __restrict__ outp, int out_is_bf16) {
    __shared__ short As[130 * 72];
    __shared__ short Bs[3 * 64 * 72];
    int tid = threadIdx.x, wv_ = tid >> 6, lane = tid & 63;
    int n15 = lane & 15, quad = lane >> 4;
    int b = blockIdx.x >> 3, mt = blockIdx.x & 7;
    int n0 = blockIdx.y * 64;
    int t0 = mt * 128;
    f32x4 acc[2][4];
    for (int i = 0; i < 2; ++i) for (int j = 0; j < 4; ++j)
        for (int p = 0; p < 4; ++p) acc[i][j][p] = 0.f;

    for (int kc = 0; kc < 4; ++kc) {
        int c0 = kc * 64;
        __syncthreads();
        if (in_is_fp32) {
            const float* in = (const float*)inp;
            for (int it = 0; it < 9; ++it) {
                int idx = tid + 256 * it;
                int row = idx >> 4, fc = idx & 15;
                if (row < 130) {
                    int t = t0 + row - 2;
                    s4v st;
                    if (t >= 0) {
                        f4 v = *reinterpret_cast<const f4*>(&in[((size_t)b * TT + t) * CC + c0 + fc * 4]);
                        for (int p = 0; p < 4; ++p) st[p] = f2bf(v[p]);
                    } else { for (int p = 0; p < 4; ++p) st[p] = 0; }
                    *reinterpret_cast<s4v*>(&As[row * 72 + fc * 4]) = st;
                }
            }
        } else {
            const short* in = (const short*)inp;
            for (int it = 0; it < 5; ++it) {
                int idx = tid + 256 * it;
                int row = idx >> 3, seg = idx & 7;
                if (row < 130) {
                    int t = t0 + row - 2;
                    s8 st;
                    if (t >= 0) st = *reinterpret_cast<const s8*>(&in[((size_t)b * TT + t) * CC + c0 + seg * 8]);
                    else for (int p = 0; p < 8; ++p) st[p] = 0;
                    *reinterpret_cast<s8*>(&As[row * 72 + seg * 8]) = st;
                }
            }
        }
        for (int it = 0; it < 6; ++it) {     // B: 192 rows (j,o) x 8 segs
            int idx = tid + 256 * it;
            int row = idx >> 3, seg = idx & 7;
            int j = row >> 6, o = row & 63;
            *reinterpret_cast<s8*>(&Bs[row * 72 + seg * 8]) =
                *reinterpret_cast<const s8*>(&wbf[((size_t)(j * 256 + n0 + o)) * 256 + c0 + seg * 8]);
        }
        __syncthreads();
        for (int j = 0; j < 3; ++j)
            for (int ks = 0; ks < 2; ++ks)
                for (int mt2 = 0; mt2 < 2; ++mt2) {
                    s8 a = *reinterpret_cast<const s8*>(&As[(wv_ * 32 + mt2 * 16 + n15 + j) * 72 + quad * 8 + ks * 32]);
                    for (int nt = 0; nt < 4; ++nt) {
                        s8 bb = *reinterpret_cast<const s8*>(&Bs[(j * 64 + nt * 16 + n15) * 72 + quad * 8 + ks * 32]);
                        acc[mt2][nt] = __builtin_amdgcn_mfma_f32_16x16x32_bf16(a, bb, acc[mt2][nt], 0, 0, 0);
                    }
                }
    }
    for (int mt2 = 0; mt2 < 2; ++mt2)
        for (int nt = 0; nt < 4; ++nt) {
            int o = n0 + nt * 16 + n15;
            float bvl = bias[o];
            for (int reg = 0; reg < 4; ++reg) {
                int t = t0 + wv_ * 32 + mt2 * 16 + quad * 4 + reg;
                float v = fmaxf(acc[mt2][nt][reg] + bvl, 0.f);
                if (out_is_bf16) ((short*)outp)[((size_t)b * TT + t) * CC + o] = f2bf(v);
                else             ((float*)outp)[((size_t)b * TT + t) * CC + o] = v;
            }
        }
}

// ---------------------------------------------------------------------------
__global__ void rowsm_kernel(const float* __restrict__ rowsum, float* __restrict__ wx) {
    __shared__ float red[256];
    int b = blockIdx.x, tid = threadIdx.x;
    float v[4];
    float m = -1e30f;
    for (int r = 0; r < 4; ++r) { v[r] = rowsum[(size_t)b * TT + tid + 256 * r]; m = fmaxf(m, v[r]); }
    red[tid] = m; __syncthreads();
    for (int s = 128; s > 0; s >>= 1) { if (tid < s) red[tid] = fmaxf(red[tid], red[tid + s]); __syncthreads(); }
    m = red[0]; __syncthreads();
    float e[4], zs = 0.f;
    for (int r = 0; r < 4; ++r) { e[r] = __expf(v[r] - m); zs += e[r]; }
    red[tid] = zs; __syncthreads();
    for (int s = 128; s > 0; s >>= 1) { if (tid < s) red[tid] += red[tid + s]; __syncthreads(); }
    float rz = 1.0f / red[0];
    for (int r = 0; r < 4; ++r) wx[(size_t)b * TT + tid + 256 * r] = e[r] * rz;
}

// ---------------------------------------------------------------------------
__global__ void final_kernel(const float* __restrict__ c2, const float* __restrict__ x,
                             const float* __restrict__ wx, float* __restrict__ out) {
    __shared__ float tile[32 * 33];
    int tid = threadIdx.x;
    int c0 = blockIdx.x * 32, t0 = blockIdx.y * 32, b = blockIdx.z;
    int tl = tid >> 3, c4 = (tid & 7) * 4;
    f4 v = *reinterpret_cast<const f4*>(&c2[((size_t)b * TT + t0 + tl) * CC + c0 + c4]);
    for (int p = 0; p < 4; ++p) tile[tl * 33 + c4 + p] = v[p];
    __syncthreads();
    int cl = tid >> 3, t4 = (tid & 7) * 4;
    f4 x4 = *reinterpret_cast<const f4*>(&x[((size_t)b * CC + c0 + cl) * TT + t0 + t4]);
    f4 w4 = *reinterpret_cast<const f4*>(&wx[(size_t)b * TT + t0 + t4]);
    f4 r;
    for (int p = 0; p < 4; ++p) {
        float cv = tile[(t4 + p) * 33 + cl];
        r[p] = fmaxf(cv + x4[p] * (1.f + w4[p]), 0.f);
    }
    *reinterpret_cast<f4*>(&out[((size_t)b * CC + c0 + cl) * TT + t0 + t4]) = r;
}

// ---------------------------------------------------------------------------
extern "C" void kernel_launch(void* const* d_in, const int* in_sizes, int n_in,
                              void* d_out, int out_size, void* d_ws, size_t ws_size,
                              hipStream_t stream) {
    (void)in_sizes; (void)n_in; (void)out_size; (void)ws_size;
    const float* x  = (const float*)d_in[0];
    const float* wq = (const float*)d_in[1];
    const float* bq = (const float*)d_in[2];
    const float* wk = (const float*)d_in[3];
    const float* bk = (const float*)d_in[4];
    const float* wv = (const float*)d_in[5];
    const float* bv = (const float*)d_in[6];
    const float* v1 = (const float*)d_in[7];
    const float* g1 = (const float*)d_in[8];
    const float* b1 = (const float*)d_in[9];
    const float* v2 = (const float*)d_in[10];
    const float* g2 = (const float*)d_in[11];
    const float* b2 = (const float*)d_in[12];
    char* ws = (char*)d_ws;
    float* out = (float*)d_out;

    short* qbf  = (short*)(ws + OFF_QBF);
    short* kbf  = (short*)(ws + OFF_KBF);
    short* vt   = (short*)(ws + OFF_VT);
    float* oa   = (float*)(ws + OFF_OA);     // out_attn fp32; later c2
    short* xt   = (short*)(ws + OFF_OA);     // xt bf16 (dead before oa written)
    short* c1   = (short*)(ws + OFF_C1);
    float* crz  = (float*)(ws + OFF_CRZ);
    float* rs   = (float*)(ws + OFF_RS);
    float* wxb  = (float*)(ws + OFF_WX);
    short* w1bf = (short*)(ws + OFF_W1);
    short* w2bf = (short*)(ws + OFF_W2);
    short* wqkv = (short*)(ws + OFF_WQKV);

    wn_kernel<<<dim3(512), dim3(256), 0, stream>>>(v1, g1, v2, g2, w1bf, w2bf);
    pack_kernel<<<dim3(96), dim3(256), 0, stream>>>(wq, wk, wv, wqkv);
    transpose_kernel<<<dim3(4, 16, 32), dim3(256), 0, stream>>>(x, xt);
    qkv_kernel<<<dim3(256, 6), dim3(256), 0, stream>>>(xt, wqkv, bq, bk, bv, qbf, kbf, vt);
    colz_kernel<<<dim3(512), dim3(256), 0, stream>>>(qbf, kbf, crz);
    attn_kernel<<<dim3(512), dim3(256), 0, stream>>>(qbf, kbf, vt, crz, oa, rs);
    conv_kernel<<<dim3(256, 4), dim3(256), 0, stream>>>(oa, 1, w1bf, b1, c1, 1);
    conv_kernel<<<dim3(256, 4), dim3(256), 0, stream>>>(c1, 0, w2bf, b2, oa, 0);
    rowsm_kernel<<<dim3(32), dim3(256), 0, stream>>>(rs, wxb);
    final_kernel<<<dim3(8, 32, 32), dim3(256), 0, stream>>>(oa, x, wxb, out);
}